// Round 17
// baseline (390.267 us; speedup 1.0000x reference)
//
#include <hip/hip_runtime.h>
#include <hip/hip_bf16.h>
#include <hip/hip_fp16.h>
#include <cstdint>
#include <cstddef>

// ---------------------------------------------------------------------------
// FeatureExtractorGAT, round 17.
// Change vs R16 (192 us; all own kernels < 43 us; est. gat1_agg ~40 us is
// the largest, node-parallel with redundant broadcast gathers + 4x-dup exp):
//   csrfill2 + gat1_agg -> csrfill_agg: one block per 128-node dst-bucket
//   streams its ebuf edges ONCE, writing csr/csrdst AND accumulating the
//   layer-1 input-space aggregation in LDS (agg[128][33] pad-33 so ds_add
//   banks spread by dst; ssum[128][9]; a_d1 bucket rows cached in LDS).
//   Per edge: 3 float4 gathers (L2-resident x + a_s1), 8 exps (once, not
//   x4), 40 ds_add_f32. Perfect edge balance; gat1_agg deleted.
// Everything else unchanged from R16.
// ---------------------------------------------------------------------------

typedef _Float16 half8 __attribute__((ext_vector_type(8)));
typedef float floatx4 __attribute__((ext_vector_type(4)));

constexpr int BSH = 7;            // 128 nodes per bucket
constexpr int MAXBUK = 512;       // supports N <= 65536

// ---- fused setup: block 0 = prep(w1t,wa2t); [1,1+NW2T) = w2t;
// [A1_0, A1_0+NA1) = a1 (self-computed wa1 in LDS); [H0, ...) = bucket_hist.
__global__ __launch_bounds__(256) void setup_kernel(
    const float* __restrict__ W1,
    const float* __restrict__ as1, const float* __restrict__ ad1,
    const float* __restrict__ W2,
    const float* __restrict__ as2, const float* __restrict__ ad2,
    const float* __restrict__ x, const int* __restrict__ ei,
    int E, int N,
    float4* __restrict__ w1t, float2* __restrict__ wa2t,
    __half* __restrict__ w2t,
    float* __restrict__ a_s1, float* __restrict__ a_d1,
    int* __restrict__ bcnt,
    int NW2T, int NA1)
{
    __shared__ int   lcnt[MAXBUK];
    __shared__ float wa1s[64];
    int b = blockIdx.x;
    int t = threadIdx.x;
    int A1_0 = 1 + NW2T;
    int H0   = A1_0 + NA1;

    if (b == 0) {
        for (int i = t; i < 480; i += 256) {
            float accs = 0.f, accd = 0.f;
            #pragma unroll 4
            for (int c = 0; c < 96; ++c) {
                float w = W2[i * 96 + c];
                accs += w * as2[c];
                accd += w * ad2[c];
            }
            wa2t[i] = make_float2(accs, accd);
            w1t[i]  = make_float4(W1[i], W1[480 + i], W1[960 + i], W1[1440 + i]);
        }
    } else if (b < A1_0) {
        int idx = (b - 1) * 256 + t;
        if (idx < 96 * 480) {
            int n = idx / 480, k = idx - n * 480;
            w2t[idx] = __float2half(W2[k * 96 + n]);
        }
    } else if (b < H0) {
        if (t < 32) {
            int k = t >> 3, h = t & 7;
            float accs = 0.f, accd = 0.f;
            for (int c = 0; c < 60; ++c) {
                float w = W1[k * 480 + h * 60 + c];
                accs += w * as1[h * 60 + c];
                accd += w * ad1[h * 60 + c];
            }
            wa1s[k * 8 + h]      = accs;
            wa1s[32 + k * 8 + h] = accd;
        }
        __syncthreads();
        int n = (b - A1_0) * 256 + t;
        if (n < N) {
            float4 xv = *(const float4*)(x + (size_t)n * 4);
            #pragma unroll
            for (int h = 0; h < 8; ++h) {
                float as = xv.x * wa1s[h] + xv.y * wa1s[8 + h]
                         + xv.z * wa1s[16 + h] + xv.w * wa1s[24 + h];
                float ad = xv.x * wa1s[32 + h] + xv.y * wa1s[40 + h]
                         + xv.z * wa1s[48 + h] + xv.w * wa1s[56 + h];
                a_s1[n * 8 + h] = as;
                a_d1[n * 8 + h] = ad;
            }
        }
    } else {
        int nbuk = (N + 127) >> BSH;
        for (int i = t; i < nbuk; i += 256) lcnt[i] = 0;
        __syncthreads();
        #pragma unroll
        for (int u = 0; u < 8; ++u) {
            int e = (b - H0) * 2048 + u * 256 + t;
            if (e < E + N) {
                int d = (e < E) ? ei[E + e] : (e - E);
                atomicAdd(&lcnt[d >> BSH], 1);
            }
        }
        __syncthreads();
        for (int i = t; i < nbuk; i += 256)
            if (lcnt[i]) atomicAdd(&bcnt[i], lcnt[i]);
    }
}

// ---- CSR build pass 2: scan bucket counts (1 block, 512 thr)
__global__ __launch_bounds__(512) void bucket_scan(const int* __restrict__ bcnt, int nbuk,
                                                   int* __restrict__ boff,
                                                   int* __restrict__ bcursor,
                                                   int* __restrict__ row_ptr, int N)
{
    __shared__ int wsum[8];
    int t = threadIdx.x, lane = t & 63, wid = t >> 6;
    int v = (t < nbuk) ? bcnt[t] : 0;
    int x = v;
    #pragma unroll
    for (int off = 1; off < 64; off <<= 1) {
        int y = __shfl_up(x, off, 64);
        if (lane >= off) x += y;
    }
    if (lane == 63) wsum[wid] = x;
    __syncthreads();
    if (wid == 0) {
        int wv = (lane < 8) ? wsum[lane] : 0;
        #pragma unroll
        for (int off = 1; off < 8; off <<= 1) {
            int y = __shfl_up(wv, off, 64);
            if (lane >= off) wv += y;
        }
        if (lane < 8) wsum[lane] = wv;
    }
    __syncthreads();
    int excl = (wid ? wsum[wid - 1] : 0) + x - v;
    if (t < nbuk) { boff[t] = excl; bcursor[t] = excl; }
    if (t == nbuk - 1) { boff[nbuk] = excl + v; row_ptr[N] = excl + v; }
}

// ---- CSR build pass 3: multisplit (src,dst) pairs into bucket regions.
__global__ __launch_bounds__(256) void multisplit(const int* __restrict__ ei, int E, int N,
                                                  int* __restrict__ bcursor,
                                                  int2* __restrict__ ebuf)
{
    __shared__ int lcnt[MAXBUK];
    __shared__ int lbase[MAXBUK];
    int t = threadIdx.x;
    int nbuk = (N + 127) >> BSH;
    for (int b = t; b < nbuk; b += 256) lcnt[b] = 0;
    __syncthreads();
    constexpr int U = 16;
    int ss[U], dd[U], rk[U];
    bool ok[U];
    #pragma unroll
    for (int u = 0; u < U; ++u) {
        int e = blockIdx.x * (256 * U) + u * 256 + t;
        ok[u] = e < E + N;
        if (ok[u]) {
            if (e < E) { ss[u] = ei[e]; dd[u] = ei[E + e]; } else { ss[u] = dd[u] = e - E; }
            rk[u] = atomicAdd(&lcnt[dd[u] >> BSH], 1);
        }
    }
    __syncthreads();
    for (int b = t; b < nbuk; b += 256)
        lbase[b] = lcnt[b] ? atomicAdd(&bcursor[b], lcnt[b]) : 0;
    __syncthreads();
    #pragma unroll
    for (int u = 0; u < U; ++u)
        if (ok[u]) ebuf[(size_t)lbase[dd[u] >> BSH] + rk[u]] = make_int2(ss[u], dd[u]);
}

// ---- CSR build pass 4 + LAYER-1 AGGREGATION, fused. One block per bucket.
// LDS: hist/cursors, a_d1 bucket rows, agg accum [128][33] (pad -> banks
// spread by dst since 33 = 1 mod 32), ssum accum [128][9].
__global__ __launch_bounds__(256) void csrfill_agg(
    const int2* __restrict__ ebuf, const int* __restrict__ boff,
    const float* __restrict__ x,
    const float* __restrict__ a_s1, const float* __restrict__ a_d1,
    int* __restrict__ row_ptr, int* __restrict__ csr, int* __restrict__ csrdst,
    float* __restrict__ agg, float* __restrict__ ssum, int N)
{
    int b = blockIdx.x;
    int node0 = b << BSH;
    int nnode = N - node0;  if (nnode > 128) nnode = 128;
    int beg = boff[b], end = boff[b + 1];
    __shared__ int   hcnt[128], hcur[128];
    __shared__ int   wends[4];
    __shared__ float ad1s[128][8];
    __shared__ float aggs[128][33];
    __shared__ float ssums[128][9];
    int t = threadIdx.x;

    if (t < 128) hcnt[t] = 0;
    for (int i = t; i < 128 * 33; i += 256) (&aggs[0][0])[i] = 0.f;
    for (int i = t; i < 128 * 9;  i += 256) (&ssums[0][0])[i] = 0.f;
    for (int i = t; i < nnode * 8; i += 256)
        ad1s[i >> 3][i & 7] = a_d1[(size_t)node0 * 8 + i];
    __syncthreads();

    // Phase B: dst histogram
    for (int i = beg + t; i < end; i += 256)
        atomicAdd(&hcnt[ebuf[i].y - node0], 1);
    __syncthreads();

    // Phase B': 128-entry scan
    int lane = t & 63, wid = t >> 6;
    int v = (t < 128) ? hcnt[t] : 0;
    int xs = v;
    #pragma unroll
    for (int off = 1; off < 64; off <<= 1) {
        int y = __shfl_up(xs, off, 64);
        if (lane >= off) xs += y;
    }
    if (lane == 63) wends[wid] = xs;
    __syncthreads();
    int excl = xs - v + ((wid == 1) ? wends[0] : 0);
    if (t < 128) {
        hcur[t] = excl;
        if (t < nnode) row_ptr[node0 + t] = beg + excl;
    }
    __syncthreads();

    // Phase C+D: write csr/csrdst AND aggregate (U=2 batches for gather MLP)
    for (int i = beg + t; i < end; i += 512) {
        int  i1 = i + 256;
        bool ok1 = i1 < end;
        int2 e0 = ebuf[i];
        int2 e1 = ok1 ? ebuf[i1] : e0;
        float4 xv0 = *(const float4*)(x + (size_t)e0.x * 4);
        float4 xv1 = *(const float4*)(x + (size_t)e1.x * 4);
        float4 asa0 = *(const float4*)(a_s1 + (size_t)e0.x * 8);
        float4 asb0 = *(const float4*)(a_s1 + (size_t)e0.x * 8 + 4);
        float4 asa1 = *(const float4*)(a_s1 + (size_t)e1.x * 8);
        float4 asb1 = *(const float4*)(a_s1 + (size_t)e1.x * 8 + 4);

        int dl0 = e0.y - node0;
        int p0 = atomicAdd(&hcur[dl0], 1);
        csr[(size_t)beg + p0]    = e0.x;
        csrdst[(size_t)beg + p0] = e0.y;
        {
            float as[8] = {asa0.x, asa0.y, asa0.z, asa0.w, asb0.x, asb0.y, asb0.z, asb0.w};
            float xv[4] = {xv0.x, xv0.y, xv0.z, xv0.w};
            #pragma unroll
            for (int h = 0; h < 8; ++h) {
                float ev = as[h] + ad1s[dl0][h];
                float pv = __expf(fmaxf(ev, 0.2f * ev));
                atomicAdd(&ssums[dl0][h], pv);
                #pragma unroll
                for (int c = 0; c < 4; ++c)
                    atomicAdd(&aggs[dl0][h * 4 + c], pv * xv[c]);
            }
        }
        if (ok1) {
            int dl1 = e1.y - node0;
            int p1 = atomicAdd(&hcur[dl1], 1);
            csr[(size_t)beg + p1]    = e1.x;
            csrdst[(size_t)beg + p1] = e1.y;
            float as[8] = {asa1.x, asa1.y, asa1.z, asa1.w, asb1.x, asb1.y, asb1.z, asb1.w};
            float xv[4] = {xv1.x, xv1.y, xv1.z, xv1.w};
            #pragma unroll
            for (int h = 0; h < 8; ++h) {
                float ev = as[h] + ad1s[dl1][h];
                float pv = __expf(fmaxf(ev, 0.2f * ev));
                atomicAdd(&ssums[dl1][h], pv);
                #pragma unroll
                for (int c = 0; c < 4; ++c)
                    atomicAdd(&aggs[dl1][h * 4 + c], pv * xv[c]);
            }
        }
    }
    __syncthreads();

    // Epilogue: flush accumulators (coalesced)
    for (int i = t; i < nnode * 32; i += 256)
        agg[(size_t)node0 * 32 + i] = aggs[i >> 5][i & 31];
    for (int i = t; i < nnode * 8; i += 256)
        ssum[(size_t)node0 * 8 + i] = ssums[i >> 3][i & 7];
}

// ---- h[n] = ELU((agg/s) @ W1_head + b1), fp16 out + fused layer-2 dots.
__global__ __launch_bounds__(256) void h_kernel(
    const float* __restrict__ agg, const float* __restrict__ ssum,
    const float4* __restrict__ w1t, const float* __restrict__ b1,
    const float2* __restrict__ wa2t,
    __half* __restrict__ h2buf, float* __restrict__ a2s, float* __restrict__ a2d, int N)
{
    __shared__ float4 w1s[480];
    __shared__ float2 wa2s[480];
    __shared__ float  b1s[480];
    int t = threadIdx.x;
    for (int i = t; i < 480; i += 256) {
        w1s[i]  = w1t[i];
        wa2s[i] = wa2t[i];
        b1s[i]  = b1[i];
    }
    __syncthreads();

    int node = blockIdx.x * 4 + (t >> 6);
    if (node >= N) return;
    int lane = t & 63;
    bool act = lane < 60;

    float psrc = 0.f, pdst = 0.f;
    #pragma unroll
    for (int h = 0; h < 8; ++h) {
        float4 ag  = *(const float4*)(agg + (size_t)node * 32 + h * 4);  // uniform
        float  inv = 1.f / (ssum[(size_t)node * 8 + h] + 1e-16f);        // uniform
        if (act) {
            int col = h * 60 + lane;
            float4 w  = w1s[col];
            float raw = ag.x * w.x + ag.y * w.y + ag.z * w.z + ag.w * w.w;
            float v   = raw * inv + b1s[col];
            float o   = v > 0.f ? v : (__expf(v) - 1.f);
            h2buf[(size_t)node * 480 + col] = __float2half(o);
            float2 wz = wa2s[col];
            psrc += o * wz.x;
            pdst += o * wz.y;
        }
    }
    #pragma unroll
    for (int off = 32; off; off >>= 1) {
        psrc += __shfl_xor(psrc, off);
        pdst += __shfl_xor(pdst, off);
    }
    if (lane == 0) { a2s[node] = psrc; a2d[node] = pdst; }
}

// ---- p2: p[e] = exp(leaky(a_s2[csr[e]] + a_d2[csrdst[e]])), edge-parallel
__global__ __launch_bounds__(256) void p2_kernel(
    const int* __restrict__ csr, const int* __restrict__ csrdst,
    const float* __restrict__ a_s2, const float* __restrict__ a_d2,
    float* __restrict__ pbuf2, int EP)
{
    int i = (blockIdx.x * 256 + threadIdx.x) * 4;
    if (i + 3 < EP) {
        int4 s4 = *(const int4*)(csr + i);
        int4 d4 = *(const int4*)(csrdst + i);
        float e0 = a_s2[s4.x] + a_d2[d4.x];
        float e1 = a_s2[s4.y] + a_d2[d4.y];
        float e2 = a_s2[s4.z] + a_d2[d4.z];
        float e3 = a_s2[s4.w] + a_d2[d4.w];
        float4 o;
        o.x = __expf(fmaxf(e0, 0.2f * e0));
        o.y = __expf(fmaxf(e1, 0.2f * e1));
        o.z = __expf(fmaxf(e2, 0.2f * e2));
        o.w = __expf(fmaxf(e3, 0.2f * e3));
        *(float4*)(pbuf2 + i) = o;
    } else {
        for (int u = 0; u < 4; ++u) {
            int e = i + u;
            if (e < EP) {
                float ev = a_s2[csr[e]] + a_d2[csrdst[e]];
                pbuf2[e] = __expf(fmaxf(ev, 0.2f * ev));
            }
        }
    }
}

// ---- xh2h[N,96] = h2[N,480] @ W2[480,96] via MFMA fp16 (f32 accum).
__global__ __launch_bounds__(256) void gemm2_mfma(
    const __half* __restrict__ h2, const __half* __restrict__ w2t,
    __half* __restrict__ xh2h, int N)
{
    int wave = threadIdx.x >> 6;
    int lane = threadIdx.x & 63;
    int m0 = blockIdx.x * 64 + wave * 16;
    int ra   = lane & 15;
    int kgrp = lane >> 4;
    int m = m0 + ra;  if (m > N - 1) m = N - 1;   // clamp: OOB rows duplicate N-1

    floatx4 acc[6];
    #pragma unroll
    for (int n = 0; n < 6; ++n) acc[n] = (floatx4){0.f, 0.f, 0.f, 0.f};

    const _Float16* arow = (const _Float16*)(h2 + (size_t)m * 480);
    const _Float16* wt   = (const _Float16*)w2t;
    for (int k0 = 0; k0 < 480; k0 += 32) {
        half8 af = *(const half8*)(arow + k0 + kgrp * 8);
        #pragma unroll
        for (int n = 0; n < 6; ++n) {
            half8 bf = *(const half8*)(wt + (size_t)(n * 16 + ra) * 480 + k0 + kgrp * 8);
            acc[n] = __builtin_amdgcn_mfma_f32_16x16x32_f16(af, bf, acc[n], 0, 0, 0);
        }
    }
    #pragma unroll
    for (int n = 0; n < 6; ++n) {
        int c = n * 16 + ra;
        #pragma unroll
        for (int j = 0; j < 4; ++j) {
            int r = m0 + kgrp * 4 + j;
            if (r < N) xh2h[(size_t)r * 96 + c] = __float2half(acc[n][j]);
        }
    }
}

// ---- GAT layer 2: wave/node; contiguous s_load batches of csr + pbuf2
// (independent), gather + cvt + 2 FMA per edge; U=16.
__global__ __launch_bounds__(256) void gat2_fused(
    const int* __restrict__ row_ptr, const int* __restrict__ csr,
    const float* __restrict__ pbuf2,
    const __half* __restrict__ xh2h, const float* __restrict__ b2,
    float* __restrict__ out, int N)
{
    int gid = blockIdx.x * blockDim.x + threadIdx.x;
    int node = gid >> 6;
    if (node >= N) return;
    int lane = threadIdx.x & 63;
    bool act = lane < 48;
    float s = 0.f, ax = 0.f, ay = 0.f;
    int beg = __builtin_amdgcn_readfirstlane(row_ptr[node]);
    int end = __builtin_amdgcn_readfirstlane(row_ptr[node + 1]);
    constexpr int U = 16;
    for (int e0 = beg; e0 < end; e0 += U) {
        int   srcs[U];
        float pv[U];
        #pragma unroll
        for (int u = 0; u < U; ++u) {
            int t = e0 + u;  if (t > end - 1) t = end - 1;      // scalar clamp
            srcs[u] = __builtin_amdgcn_readfirstlane(csr[t]);
            float pr = __uint_as_float(
                __builtin_amdgcn_readfirstlane(__float_as_uint(pbuf2[t])));
            pv[u] = (e0 + u < end) ? pr : 0.f;                  // uniform select
        }
        __half2 gv[U];
        if (act) {
            #pragma unroll
            for (int u = 0; u < U; ++u)
                gv[u] = ((const __half2*)(xh2h + (size_t)srcs[u] * 96))[lane];
        }
        #pragma unroll
        for (int u = 0; u < U; ++u) {
            s += pv[u];
            if (act) {
                float2 fg = __half22float2(gv[u]);
                ax += pv[u] * fg.x;
                ay += pv[u] * fg.y;
            }
        }
    }
    float inv = 1.f / (s + 1e-16f);
    if (act) {
        out[(size_t)node * 96 + 2 * lane]     = ax * inv + b2[2 * lane];
        out[(size_t)node * 96 + 2 * lane + 1] = ay * inv + b2[2 * lane + 1];
    }
}

extern "C" void kernel_launch(void* const* d_in, const int* in_sizes, int n_in,
                              void* d_out, int out_size, void* d_ws, size_t ws_size,
                              hipStream_t stream)
{
    const float* x   = (const float*)d_in[0];
    const int*   ei  = (const int*)  d_in[1];
    const float* W1  = (const float*)d_in[2];
    const float* as1 = (const float*)d_in[3];
    const float* ad1 = (const float*)d_in[4];
    const float* b1  = (const float*)d_in[5];
    const float* W2  = (const float*)d_in[6];
    const float* as2 = (const float*)d_in[7];
    const float* ad2 = (const float*)d_in[8];
    const float* b2  = (const float*)d_in[9];
    float* out = (float*)d_out;

    int N  = in_sizes[0] / 4;   // 50000
    int E  = in_sizes[1] / 2;   // 800000
    int EP = E + N;
    int NBUK  = (N + 127) >> BSH;           // 391
    int NW2T  = (96 * 480 + 255) / 256;     // 180
    int NA1   = (N + 255) / 256;            // 196
    int NBK_H = (EP + 2047) / 2048;         // 416
    int NBK_M = (EP + 4095) / 4096;         // multisplit blocks (U=16)
    int NSETUP = 1 + NW2T + NA1 + NBK_H;

    float* f = (float*)d_ws;
    float* a_s1  = f;  f += (size_t)N * 8;
    float* a_d1  = f;  f += (size_t)N * 8;
    float* agg   = f;  f += (size_t)N * 32;
    float* ssum  = f;  f += (size_t)N * 8;
    float* a_s2  = f;  f += N;
    float* a_d2  = f;  f += N;
    float4* w1t  = (float4*)f;  f += 480 * 4;
    float2* wa2t = (float2*)f;  f += 480 * 2;
    __half* h2buf = (__half*)f;
    __half* hp   = h2buf + (size_t)N * 480;
    __half* xh2h = hp;   hp += (size_t)N * 96;
    __half* w2t  = hp;   hp += 96 * 480;
    int2* ebuf   = (int2*)hp;
    int* ip      = (int*)(ebuf + EP);
    int* row_ptr = ip;  ip += N + 1;
    int* bcnt    = ip;  ip += MAXBUK;
    int* boff    = ip;  ip += MAXBUK + 1;
    int* bcursor = ip;  ip += MAXBUK;
    int* csr     = ip;  ip += EP;
    int* csrdst  = ip;  ip += EP;
    float* pbuf2 = (float*)ip;  ip += EP;

    size_t needed = (size_t)((char*)ip - (char*)d_ws);
    if (needed > ws_size) return;  // loud failure if scratch too small

    hipMemsetAsync(bcnt, 0, MAXBUK * sizeof(int), stream);
    setup_kernel<<<NSETUP, 256, 0, stream>>>(
        W1, as1, ad1, W2, as2, ad2, x, ei, E, N,
        w1t, wa2t, w2t, a_s1, a_d1, bcnt, NW2T, NA1);
    bucket_scan<<<1, 512, 0, stream>>>(bcnt, NBUK, boff, bcursor, row_ptr, N);
    multisplit<<<NBK_M, 256, 0, stream>>>(ei, E, N, bcursor, ebuf);
    csrfill_agg<<<NBUK, 256, 0, stream>>>(
        ebuf, boff, x, a_s1, a_d1, row_ptr, csr, csrdst, agg, ssum, N);
    h_kernel<<<(N + 3) / 4, 256, 0, stream>>>(
        agg, ssum, w1t, b1, wa2t, h2buf, a_s2, a_d2, N);
    p2_kernel<<<(EP + 1023) / 1024, 256, 0, stream>>>(
        csr, csrdst, a_s2, a_d2, pbuf2, EP);
    gemm2_mfma<<<(N + 63) / 64, 256, 0, stream>>>(h2buf, w2t, xh2h, N);
    gat2_fused<<<(N * 64 + 255) / 256, 256, 0, stream>>>(
        row_ptr, csr, pbuf2, xh2h, b2, out, N);
}

// Round 18
// 191.904 us; speedup vs baseline: 2.0337x; 2.0337x over previous
//
#include <hip/hip_runtime.h>
#include <hip/hip_bf16.h>
#include <hip/hip_fp16.h>
#include <cstdint>
#include <cstddef>

// ---------------------------------------------------------------------------
// FeatureExtractorGAT, round 18 = R16 revert + gat1_agg U=8.
// R17 post-mortem: csrfill_agg fusion regressed 192->390 us (csrfill_agg
// 239 us @ VALU 1.3% / occ 12.5% / 432k LDS bank conflicts): random-dst LDS
// float atomics SERIALIZE on same-address collisions, and 27KB LDS at 391
// blocks killed occupancy. Lesson: LDS atomics with data-dependent addresses
// are contention-bound. Reverted to the separate csrfill2 + gat1_agg.
// Single change vs R16: gat1_agg U=4->8 (deeper gather MLP, latency-bound).
// ---------------------------------------------------------------------------

typedef _Float16 half8 __attribute__((ext_vector_type(8)));
typedef float floatx4 __attribute__((ext_vector_type(4)));

constexpr int BSH = 7;            // 128 nodes per bucket
constexpr int MAXBUK = 512;       // supports N <= 65536

// ---- fused setup: block 0 = prep(w1t,wa2t); [1,1+NW2T) = w2t;
// [A1_0, A1_0+NA1) = a1 (self-computed wa1 in LDS); [H0, ...) = bucket_hist.
__global__ __launch_bounds__(256) void setup_kernel(
    const float* __restrict__ W1,
    const float* __restrict__ as1, const float* __restrict__ ad1,
    const float* __restrict__ W2,
    const float* __restrict__ as2, const float* __restrict__ ad2,
    const float* __restrict__ x, const int* __restrict__ ei,
    int E, int N,
    float4* __restrict__ w1t, float2* __restrict__ wa2t,
    __half* __restrict__ w2t,
    float* __restrict__ a_s1, float* __restrict__ a_d1,
    int* __restrict__ bcnt,
    int NW2T, int NA1)
{
    __shared__ int   lcnt[MAXBUK];
    __shared__ float wa1s[64];
    int b = blockIdx.x;
    int t = threadIdx.x;
    int A1_0 = 1 + NW2T;
    int H0   = A1_0 + NA1;

    if (b == 0) {
        for (int i = t; i < 480; i += 256) {
            float accs = 0.f, accd = 0.f;
            #pragma unroll 4
            for (int c = 0; c < 96; ++c) {
                float w = W2[i * 96 + c];
                accs += w * as2[c];
                accd += w * ad2[c];
            }
            wa2t[i] = make_float2(accs, accd);
            w1t[i]  = make_float4(W1[i], W1[480 + i], W1[960 + i], W1[1440 + i]);
        }
    } else if (b < A1_0) {
        int idx = (b - 1) * 256 + t;
        if (idx < 96 * 480) {
            int n = idx / 480, k = idx - n * 480;
            w2t[idx] = __float2half(W2[k * 96 + n]);
        }
    } else if (b < H0) {
        if (t < 32) {
            int k = t >> 3, h = t & 7;
            float accs = 0.f, accd = 0.f;
            for (int c = 0; c < 60; ++c) {
                float w = W1[k * 480 + h * 60 + c];
                accs += w * as1[h * 60 + c];
                accd += w * ad1[h * 60 + c];
            }
            wa1s[k * 8 + h]      = accs;
            wa1s[32 + k * 8 + h] = accd;
        }
        __syncthreads();
        int n = (b - A1_0) * 256 + t;
        if (n < N) {
            float4 xv = *(const float4*)(x + (size_t)n * 4);
            #pragma unroll
            for (int h = 0; h < 8; ++h) {
                float as = xv.x * wa1s[h] + xv.y * wa1s[8 + h]
                         + xv.z * wa1s[16 + h] + xv.w * wa1s[24 + h];
                float ad = xv.x * wa1s[32 + h] + xv.y * wa1s[40 + h]
                         + xv.z * wa1s[48 + h] + xv.w * wa1s[56 + h];
                a_s1[n * 8 + h] = as;
                a_d1[n * 8 + h] = ad;
            }
        }
    } else {
        int nbuk = (N + 127) >> BSH;
        for (int i = t; i < nbuk; i += 256) lcnt[i] = 0;
        __syncthreads();
        #pragma unroll
        for (int u = 0; u < 8; ++u) {
            int e = (b - H0) * 2048 + u * 256 + t;
            if (e < E + N) {
                int d = (e < E) ? ei[E + e] : (e - E);
                atomicAdd(&lcnt[d >> BSH], 1);
            }
        }
        __syncthreads();
        for (int i = t; i < nbuk; i += 256)
            if (lcnt[i]) atomicAdd(&bcnt[i], lcnt[i]);
    }
}

// ---- CSR build pass 2: scan bucket counts (1 block, 512 thr)
__global__ __launch_bounds__(512) void bucket_scan(const int* __restrict__ bcnt, int nbuk,
                                                   int* __restrict__ boff,
                                                   int* __restrict__ bcursor,
                                                   int* __restrict__ row_ptr, int N)
{
    __shared__ int wsum[8];
    int t = threadIdx.x, lane = t & 63, wid = t >> 6;
    int v = (t < nbuk) ? bcnt[t] : 0;
    int x = v;
    #pragma unroll
    for (int off = 1; off < 64; off <<= 1) {
        int y = __shfl_up(x, off, 64);
        if (lane >= off) x += y;
    }
    if (lane == 63) wsum[wid] = x;
    __syncthreads();
    if (wid == 0) {
        int wv = (lane < 8) ? wsum[lane] : 0;
        #pragma unroll
        for (int off = 1; off < 8; off <<= 1) {
            int y = __shfl_up(wv, off, 64);
            if (lane >= off) wv += y;
        }
        if (lane < 8) wsum[lane] = wv;
    }
    __syncthreads();
    int excl = (wid ? wsum[wid - 1] : 0) + x - v;
    if (t < nbuk) { boff[t] = excl; bcursor[t] = excl; }
    if (t == nbuk - 1) { boff[nbuk] = excl + v; row_ptr[N] = excl + v; }
}

// ---- CSR build pass 3: multisplit (src,dst) pairs into bucket regions.
__global__ __launch_bounds__(256) void multisplit(const int* __restrict__ ei, int E, int N,
                                                  int* __restrict__ bcursor,
                                                  int2* __restrict__ ebuf)
{
    __shared__ int lcnt[MAXBUK];
    __shared__ int lbase[MAXBUK];
    int t = threadIdx.x;
    int nbuk = (N + 127) >> BSH;
    for (int b = t; b < nbuk; b += 256) lcnt[b] = 0;
    __syncthreads();
    constexpr int U = 16;
    int ss[U], dd[U], rk[U];
    bool ok[U];
    #pragma unroll
    for (int u = 0; u < U; ++u) {
        int e = blockIdx.x * (256 * U) + u * 256 + t;
        ok[u] = e < E + N;
        if (ok[u]) {
            if (e < E) { ss[u] = ei[e]; dd[u] = ei[E + e]; } else { ss[u] = dd[u] = e - E; }
            rk[u] = atomicAdd(&lcnt[dd[u] >> BSH], 1);
        }
    }
    __syncthreads();
    for (int b = t; b < nbuk; b += 256)
        lbase[b] = lcnt[b] ? atomicAdd(&bcursor[b], lcnt[b]) : 0;
    __syncthreads();
    #pragma unroll
    for (int u = 0; u < U; ++u)
        if (ok[u]) ebuf[(size_t)lbase[dd[u] >> BSH] + rk[u]] = make_int2(ss[u], dd[u]);
}

// ---- CSR build pass 4: one block per bucket; cursors in LDS; writes
// csr AND csrdst (dst companion, needed by p2_kernel).
__global__ __launch_bounds__(256) void csrfill2(const int2* __restrict__ ebuf,
                                                const int* __restrict__ boff,
                                                int* __restrict__ row_ptr,
                                                int* __restrict__ csr,
                                                int* __restrict__ csrdst, int N)
{
    int b = blockIdx.x;
    int node0 = b << BSH;
    int nnode = N - node0;  if (nnode > 128) nnode = 128;
    int beg = boff[b], end = boff[b + 1];
    __shared__ int hcnt[128], hcur[128];
    __shared__ int wends[4];
    int t = threadIdx.x;
    if (t < 128) hcnt[t] = 0;
    __syncthreads();
    for (int i = beg + t; i < end; i += 256)
        atomicAdd(&hcnt[ebuf[i].y - node0], 1);
    __syncthreads();
    int lane = t & 63, wid = t >> 6;
    int v = (t < 128) ? hcnt[t] : 0;
    int x = v;
    #pragma unroll
    for (int off = 1; off < 64; off <<= 1) {
        int y = __shfl_up(x, off, 64);
        if (lane >= off) x += y;
    }
    if (lane == 63) wends[wid] = x;
    __syncthreads();
    int excl = x - v + ((wid == 1) ? wends[0] : 0);
    if (t < 128) {
        hcur[t] = excl;
        if (t < nnode) row_ptr[node0 + t] = beg + excl;
    }
    __syncthreads();
    for (int i = beg + t; i < end; i += 256) {
        int2 e = ebuf[i];
        int p = atomicAdd(&hcur[e.y - node0], 1);
        csr[(size_t)beg + p]    = e.x;
        csrdst[(size_t)beg + p] = e.y;
    }
}

// ---- GAT layer 1 aggregation in INPUT space; U=8 edge batches per half.
__global__ __launch_bounds__(256) void gat1_agg(
    const int* __restrict__ row_ptr, const int* __restrict__ csr,
    const float* __restrict__ x,
    const float* __restrict__ a_s1, const float* __restrict__ a_d1,
    float* __restrict__ agg, float* __restrict__ ssum, int N)
{
    int gid = blockIdx.x * blockDim.x + threadIdx.x;
    int node = gid >> 6;
    if (node >= N) return;
    int lane = threadIdx.x & 63;
    int half = lane >> 5;
    int sl   = lane & 31;
    int h = sl >> 2, c = sl & 3;
    float adh = a_d1[(size_t)node * 8 + h];

    float aggv = 0.f, sv = 0.f;
    int beg = row_ptr[node], end = row_ptr[node + 1];
    constexpr int U = 8;
    for (int base = beg; base < end; base += 2 * U) {
        int   idx[U];
        float msk[U];
        #pragma unroll
        for (int u = 0; u < U; ++u) {
            int t = base + 2 * u + half;
            msk[u] = (t < end) ? 1.f : 0.f;
            idx[u] = csr[t < end ? t : (end - 1)];
        }
        float xv[U], av[U];
        #pragma unroll
        for (int u = 0; u < U; ++u) xv[u] = x[(size_t)idx[u] * 4 + c];
        #pragma unroll
        for (int u = 0; u < U; ++u) av[u] = a_s1[(size_t)idx[u] * 8 + h];
        #pragma unroll
        for (int u = 0; u < U; ++u) {
            float ev = av[u] + adh;
            ev = ev > 0.f ? ev : 0.2f * ev;
            float p = __expf(ev) * msk[u];
            sv   += p;
            aggv += p * xv[u];
        }
    }
    aggv += __shfl_xor(aggv, 32);
    sv   += __shfl_xor(sv, 32);
    if (lane < 32) {
        agg[(size_t)node * 32 + lane] = aggv;
        if (c == 0) ssum[(size_t)node * 8 + h] = sv;
    }
}

// ---- h[n] = ELU((agg/s) @ W1_head + b1), fp16 out + fused layer-2 dots.
__global__ __launch_bounds__(256) void h_kernel(
    const float* __restrict__ agg, const float* __restrict__ ssum,
    const float4* __restrict__ w1t, const float* __restrict__ b1,
    const float2* __restrict__ wa2t,
    __half* __restrict__ h2buf, float* __restrict__ a2s, float* __restrict__ a2d, int N)
{
    __shared__ float4 w1s[480];
    __shared__ float2 wa2s[480];
    __shared__ float  b1s[480];
    int t = threadIdx.x;
    for (int i = t; i < 480; i += 256) {
        w1s[i]  = w1t[i];
        wa2s[i] = wa2t[i];
        b1s[i]  = b1[i];
    }
    __syncthreads();

    int node = blockIdx.x * 4 + (t >> 6);
    if (node >= N) return;
    int lane = t & 63;
    bool act = lane < 60;

    float psrc = 0.f, pdst = 0.f;
    #pragma unroll
    for (int h = 0; h < 8; ++h) {
        float4 ag  = *(const float4*)(agg + (size_t)node * 32 + h * 4);  // uniform
        float  inv = 1.f / (ssum[(size_t)node * 8 + h] + 1e-16f);        // uniform
        if (act) {
            int col = h * 60 + lane;
            float4 w  = w1s[col];
            float raw = ag.x * w.x + ag.y * w.y + ag.z * w.z + ag.w * w.w;
            float v   = raw * inv + b1s[col];
            float o   = v > 0.f ? v : (__expf(v) - 1.f);
            h2buf[(size_t)node * 480 + col] = __float2half(o);
            float2 wz = wa2s[col];
            psrc += o * wz.x;
            pdst += o * wz.y;
        }
    }
    #pragma unroll
    for (int off = 32; off; off >>= 1) {
        psrc += __shfl_xor(psrc, off);
        pdst += __shfl_xor(pdst, off);
    }
    if (lane == 0) { a2s[node] = psrc; a2d[node] = pdst; }
}

// ---- p2: p[e] = exp(leaky(a_s2[csr[e]] + a_d2[csrdst[e]])), edge-parallel
__global__ __launch_bounds__(256) void p2_kernel(
    const int* __restrict__ csr, const int* __restrict__ csrdst,
    const float* __restrict__ a_s2, const float* __restrict__ a_d2,
    float* __restrict__ pbuf2, int EP)
{
    int i = (blockIdx.x * 256 + threadIdx.x) * 4;
    if (i + 3 < EP) {
        int4 s4 = *(const int4*)(csr + i);
        int4 d4 = *(const int4*)(csrdst + i);
        float e0 = a_s2[s4.x] + a_d2[d4.x];
        float e1 = a_s2[s4.y] + a_d2[d4.y];
        float e2 = a_s2[s4.z] + a_d2[d4.z];
        float e3 = a_s2[s4.w] + a_d2[d4.w];
        float4 o;
        o.x = __expf(fmaxf(e0, 0.2f * e0));
        o.y = __expf(fmaxf(e1, 0.2f * e1));
        o.z = __expf(fmaxf(e2, 0.2f * e2));
        o.w = __expf(fmaxf(e3, 0.2f * e3));
        *(float4*)(pbuf2 + i) = o;
    } else {
        for (int u = 0; u < 4; ++u) {
            int e = i + u;
            if (e < EP) {
                float ev = a_s2[csr[e]] + a_d2[csrdst[e]];
                pbuf2[e] = __expf(fmaxf(ev, 0.2f * ev));
            }
        }
    }
}

// ---- xh2h[N,96] = h2[N,480] @ W2[480,96] via MFMA fp16 (f32 accum).
__global__ __launch_bounds__(256) void gemm2_mfma(
    const __half* __restrict__ h2, const __half* __restrict__ w2t,
    __half* __restrict__ xh2h, int N)
{
    int wave = threadIdx.x >> 6;
    int lane = threadIdx.x & 63;
    int m0 = blockIdx.x * 64 + wave * 16;
    int ra   = lane & 15;
    int kgrp = lane >> 4;
    int m = m0 + ra;  if (m > N - 1) m = N - 1;   // clamp: OOB rows duplicate N-1

    floatx4 acc[6];
    #pragma unroll
    for (int n = 0; n < 6; ++n) acc[n] = (floatx4){0.f, 0.f, 0.f, 0.f};

    const _Float16* arow = (const _Float16*)(h2 + (size_t)m * 480);
    const _Float16* wt   = (const _Float16*)w2t;
    for (int k0 = 0; k0 < 480; k0 += 32) {
        half8 af = *(const half8*)(arow + k0 + kgrp * 8);
        #pragma unroll
        for (int n = 0; n < 6; ++n) {
            half8 bf = *(const half8*)(wt + (size_t)(n * 16 + ra) * 480 + k0 + kgrp * 8);
            acc[n] = __builtin_amdgcn_mfma_f32_16x16x32_f16(af, bf, acc[n], 0, 0, 0);
        }
    }
    #pragma unroll
    for (int n = 0; n < 6; ++n) {
        int c = n * 16 + ra;
        #pragma unroll
        for (int j = 0; j < 4; ++j) {
            int r = m0 + kgrp * 4 + j;
            if (r < N) xh2h[(size_t)r * 96 + c] = __float2half(acc[n][j]);
        }
    }
}

// ---- GAT layer 2: wave/node; contiguous s_load batches of csr + pbuf2
// (independent), gather + cvt + 2 FMA per edge; U=16.
__global__ __launch_bounds__(256) void gat2_fused(
    const int* __restrict__ row_ptr, const int* __restrict__ csr,
    const float* __restrict__ pbuf2,
    const __half* __restrict__ xh2h, const float* __restrict__ b2,
    float* __restrict__ out, int N)
{
    int gid = blockIdx.x * blockDim.x + threadIdx.x;
    int node = gid >> 6;
    if (node >= N) return;
    int lane = threadIdx.x & 63;
    bool act = lane < 48;
    float s = 0.f, ax = 0.f, ay = 0.f;
    int beg = __builtin_amdgcn_readfirstlane(row_ptr[node]);
    int end = __builtin_amdgcn_readfirstlane(row_ptr[node + 1]);
    constexpr int U = 16;
    for (int e0 = beg; e0 < end; e0 += U) {
        int   srcs[U];
        float pv[U];
        #pragma unroll
        for (int u = 0; u < U; ++u) {
            int t = e0 + u;  if (t > end - 1) t = end - 1;      // scalar clamp
            srcs[u] = __builtin_amdgcn_readfirstlane(csr[t]);
            float pr = __uint_as_float(
                __builtin_amdgcn_readfirstlane(__float_as_uint(pbuf2[t])));
            pv[u] = (e0 + u < end) ? pr : 0.f;                  // uniform select
        }
        __half2 gv[U];
        if (act) {
            #pragma unroll
            for (int u = 0; u < U; ++u)
                gv[u] = ((const __half2*)(xh2h + (size_t)srcs[u] * 96))[lane];
        }
        #pragma unroll
        for (int u = 0; u < U; ++u) {
            s += pv[u];
            if (act) {
                float2 fg = __half22float2(gv[u]);
                ax += pv[u] * fg.x;
                ay += pv[u] * fg.y;
            }
        }
    }
    float inv = 1.f / (s + 1e-16f);
    if (act) {
        out[(size_t)node * 96 + 2 * lane]     = ax * inv + b2[2 * lane];
        out[(size_t)node * 96 + 2 * lane + 1] = ay * inv + b2[2 * lane + 1];
    }
}

extern "C" void kernel_launch(void* const* d_in, const int* in_sizes, int n_in,
                              void* d_out, int out_size, void* d_ws, size_t ws_size,
                              hipStream_t stream)
{
    const float* x   = (const float*)d_in[0];
    const int*   ei  = (const int*)  d_in[1];
    const float* W1  = (const float*)d_in[2];
    const float* as1 = (const float*)d_in[3];
    const float* ad1 = (const float*)d_in[4];
    const float* b1  = (const float*)d_in[5];
    const float* W2  = (const float*)d_in[6];
    const float* as2 = (const float*)d_in[7];
    const float* ad2 = (const float*)d_in[8];
    const float* b2  = (const float*)d_in[9];
    float* out = (float*)d_out;

    int N  = in_sizes[0] / 4;   // 50000
    int E  = in_sizes[1] / 2;   // 800000
    int EP = E + N;
    int NBUK  = (N + 127) >> BSH;           // 391
    int NW2T  = (96 * 480 + 255) / 256;     // 180
    int NA1   = (N + 255) / 256;            // 196
    int NBK_H = (EP + 2047) / 2048;         // 416
    int NBK_M = (EP + 4095) / 4096;         // multisplit blocks (U=16)
    int NSETUP = 1 + NW2T + NA1 + NBK_H;

    float* f = (float*)d_ws;
    float* a_s1  = f;  f += (size_t)N * 8;
    float* a_d1  = f;  f += (size_t)N * 8;
    float* agg   = f;  f += (size_t)N * 32;
    float* ssum  = f;  f += (size_t)N * 8;
    float* a_s2  = f;  f += N;
    float* a_d2  = f;  f += N;
    float4* w1t  = (float4*)f;  f += 480 * 4;
    float2* wa2t = (float2*)f;  f += 480 * 2;
    __half* h2buf = (__half*)f;
    __half* hp   = h2buf + (size_t)N * 480;
    __half* xh2h = hp;   hp += (size_t)N * 96;
    __half* w2t  = hp;   hp += 96 * 480;
    int2* ebuf   = (int2*)hp;
    int* ip      = (int*)(ebuf + EP);
    int* row_ptr = ip;  ip += N + 1;
    int* bcnt    = ip;  ip += MAXBUK;
    int* boff    = ip;  ip += MAXBUK + 1;
    int* bcursor = ip;  ip += MAXBUK;
    int* csr     = ip;  ip += EP;
    int* csrdst  = ip;  ip += EP;
    float* pbuf2 = (float*)ip;  ip += EP;

    size_t needed = (size_t)((char*)ip - (char*)d_ws);
    if (needed > ws_size) return;  // loud failure if scratch too small

    hipMemsetAsync(bcnt, 0, MAXBUK * sizeof(int), stream);
    setup_kernel<<<NSETUP, 256, 0, stream>>>(
        W1, as1, ad1, W2, as2, ad2, x, ei, E, N,
        w1t, wa2t, w2t, a_s1, a_d1, bcnt, NW2T, NA1);
    bucket_scan<<<1, 512, 0, stream>>>(bcnt, NBUK, boff, bcursor, row_ptr, N);
    multisplit<<<NBK_M, 256, 0, stream>>>(ei, E, N, bcursor, ebuf);
    csrfill2<<<NBUK, 256, 0, stream>>>(ebuf, boff, row_ptr, csr, csrdst, N);
    gat1_agg<<<(N * 64 + 255) / 256, 256, 0, stream>>>(
        row_ptr, csr, x, a_s1, a_d1, agg, ssum, N);
    h_kernel<<<(N + 3) / 4, 256, 0, stream>>>(
        agg, ssum, w1t, b1, wa2t, h2buf, a_s2, a_d2, N);
    p2_kernel<<<(EP + 1023) / 1024, 256, 0, stream>>>(
        csr, csrdst, a_s2, a_d2, pbuf2, EP);
    gemm2_mfma<<<(N + 63) / 64, 256, 0, stream>>>(h2buf, w2t, xh2h, N);
    gat2_fused<<<(N * 64 + 255) / 256, 256, 0, stream>>>(
        row_ptr, csr, pbuf2, xh2h, b2, out, N);
}

// Round 19
// 188.355 us; speedup vs baseline: 2.0720x; 1.0188x over previous
//
#include <hip/hip_runtime.h>
#include <hip/hip_bf16.h>
#include <hip/hip_fp16.h>
#include <cstdint>
#include <cstddef>

// ---------------------------------------------------------------------------
// FeatureExtractorGAT, round 19.
// Single change vs R18 (192 us): rocprof showed the 2KB hipMemsetAsync(bcnt)
// becomes a ~43 us __amd_rocclr_fillBufferAligned dispatch INSIDE every graph
// replay (WRITE_SIZE=2.0KB rows, adjacent-replay timestamps). Replaced with
// a one-block zero_bcnt kernel (~2-3 us). Everything else byte-identical
// to R18 (R16 structure + gat1_agg U=8, which measured neutral).
// ---------------------------------------------------------------------------

typedef _Float16 half8 __attribute__((ext_vector_type(8)));
typedef float floatx4 __attribute__((ext_vector_type(4)));

constexpr int BSH = 7;            // 128 nodes per bucket
constexpr int MAXBUK = 512;       // supports N <= 65536

__global__ void zero_bcnt(int* __restrict__ bcnt)
{
    bcnt[threadIdx.x] = 0;        // MAXBUK = 512 = blockDim
}

// ---- fused setup: block 0 = prep(w1t,wa2t); [1,1+NW2T) = w2t;
// [A1_0, A1_0+NA1) = a1 (self-computed wa1 in LDS); [H0, ...) = bucket_hist.
__global__ __launch_bounds__(256) void setup_kernel(
    const float* __restrict__ W1,
    const float* __restrict__ as1, const float* __restrict__ ad1,
    const float* __restrict__ W2,
    const float* __restrict__ as2, const float* __restrict__ ad2,
    const float* __restrict__ x, const int* __restrict__ ei,
    int E, int N,
    float4* __restrict__ w1t, float2* __restrict__ wa2t,
    __half* __restrict__ w2t,
    float* __restrict__ a_s1, float* __restrict__ a_d1,
    int* __restrict__ bcnt,
    int NW2T, int NA1)
{
    __shared__ int   lcnt[MAXBUK];
    __shared__ float wa1s[64];
    int b = blockIdx.x;
    int t = threadIdx.x;
    int A1_0 = 1 + NW2T;
    int H0   = A1_0 + NA1;

    if (b == 0) {
        for (int i = t; i < 480; i += 256) {
            float accs = 0.f, accd = 0.f;
            #pragma unroll 4
            for (int c = 0; c < 96; ++c) {
                float w = W2[i * 96 + c];
                accs += w * as2[c];
                accd += w * ad2[c];
            }
            wa2t[i] = make_float2(accs, accd);
            w1t[i]  = make_float4(W1[i], W1[480 + i], W1[960 + i], W1[1440 + i]);
        }
    } else if (b < A1_0) {
        int idx = (b - 1) * 256 + t;
        if (idx < 96 * 480) {
            int n = idx / 480, k = idx - n * 480;
            w2t[idx] = __float2half(W2[k * 96 + n]);
        }
    } else if (b < H0) {
        if (t < 32) {
            int k = t >> 3, h = t & 7;
            float accs = 0.f, accd = 0.f;
            for (int c = 0; c < 60; ++c) {
                float w = W1[k * 480 + h * 60 + c];
                accs += w * as1[h * 60 + c];
                accd += w * ad1[h * 60 + c];
            }
            wa1s[k * 8 + h]      = accs;
            wa1s[32 + k * 8 + h] = accd;
        }
        __syncthreads();
        int n = (b - A1_0) * 256 + t;
        if (n < N) {
            float4 xv = *(const float4*)(x + (size_t)n * 4);
            #pragma unroll
            for (int h = 0; h < 8; ++h) {
                float as = xv.x * wa1s[h] + xv.y * wa1s[8 + h]
                         + xv.z * wa1s[16 + h] + xv.w * wa1s[24 + h];
                float ad = xv.x * wa1s[32 + h] + xv.y * wa1s[40 + h]
                         + xv.z * wa1s[48 + h] + xv.w * wa1s[56 + h];
                a_s1[n * 8 + h] = as;
                a_d1[n * 8 + h] = ad;
            }
        }
    } else {
        int nbuk = (N + 127) >> BSH;
        for (int i = t; i < nbuk; i += 256) lcnt[i] = 0;
        __syncthreads();
        #pragma unroll
        for (int u = 0; u < 8; ++u) {
            int e = (b - H0) * 2048 + u * 256 + t;
            if (e < E + N) {
                int d = (e < E) ? ei[E + e] : (e - E);
                atomicAdd(&lcnt[d >> BSH], 1);
            }
        }
        __syncthreads();
        for (int i = t; i < nbuk; i += 256)
            if (lcnt[i]) atomicAdd(&bcnt[i], lcnt[i]);
    }
}

// ---- CSR build pass 2: scan bucket counts (1 block, 512 thr)
__global__ __launch_bounds__(512) void bucket_scan(const int* __restrict__ bcnt, int nbuk,
                                                   int* __restrict__ boff,
                                                   int* __restrict__ bcursor,
                                                   int* __restrict__ row_ptr, int N)
{
    __shared__ int wsum[8];
    int t = threadIdx.x, lane = t & 63, wid = t >> 6;
    int v = (t < nbuk) ? bcnt[t] : 0;
    int x = v;
    #pragma unroll
    for (int off = 1; off < 64; off <<= 1) {
        int y = __shfl_up(x, off, 64);
        if (lane >= off) x += y;
    }
    if (lane == 63) wsum[wid] = x;
    __syncthreads();
    if (wid == 0) {
        int wv = (lane < 8) ? wsum[lane] : 0;
        #pragma unroll
        for (int off = 1; off < 8; off <<= 1) {
            int y = __shfl_up(wv, off, 64);
            if (lane >= off) wv += y;
        }
        if (lane < 8) wsum[lane] = wv;
    }
    __syncthreads();
    int excl = (wid ? wsum[wid - 1] : 0) + x - v;
    if (t < nbuk) { boff[t] = excl; bcursor[t] = excl; }
    if (t == nbuk - 1) { boff[nbuk] = excl + v; row_ptr[N] = excl + v; }
}

// ---- CSR build pass 3: multisplit (src,dst) pairs into bucket regions.
__global__ __launch_bounds__(256) void multisplit(const int* __restrict__ ei, int E, int N,
                                                  int* __restrict__ bcursor,
                                                  int2* __restrict__ ebuf)
{
    __shared__ int lcnt[MAXBUK];
    __shared__ int lbase[MAXBUK];
    int t = threadIdx.x;
    int nbuk = (N + 127) >> BSH;
    for (int b = t; b < nbuk; b += 256) lcnt[b] = 0;
    __syncthreads();
    constexpr int U = 16;
    int ss[U], dd[U], rk[U];
    bool ok[U];
    #pragma unroll
    for (int u = 0; u < U; ++u) {
        int e = blockIdx.x * (256 * U) + u * 256 + t;
        ok[u] = e < E + N;
        if (ok[u]) {
            if (e < E) { ss[u] = ei[e]; dd[u] = ei[E + e]; } else { ss[u] = dd[u] = e - E; }
            rk[u] = atomicAdd(&lcnt[dd[u] >> BSH], 1);
        }
    }
    __syncthreads();
    for (int b = t; b < nbuk; b += 256)
        lbase[b] = lcnt[b] ? atomicAdd(&bcursor[b], lcnt[b]) : 0;
    __syncthreads();
    #pragma unroll
    for (int u = 0; u < U; ++u)
        if (ok[u]) ebuf[(size_t)lbase[dd[u] >> BSH] + rk[u]] = make_int2(ss[u], dd[u]);
}

// ---- CSR build pass 4: one block per bucket; cursors in LDS; writes
// csr AND csrdst (dst companion, needed by p2_kernel).
__global__ __launch_bounds__(256) void csrfill2(const int2* __restrict__ ebuf,
                                                const int* __restrict__ boff,
                                                int* __restrict__ row_ptr,
                                                int* __restrict__ csr,
                                                int* __restrict__ csrdst, int N)
{
    int b = blockIdx.x;
    int node0 = b << BSH;
    int nnode = N - node0;  if (nnode > 128) nnode = 128;
    int beg = boff[b], end = boff[b + 1];
    __shared__ int hcnt[128], hcur[128];
    __shared__ int wends[4];
    int t = threadIdx.x;
    if (t < 128) hcnt[t] = 0;
    __syncthreads();
    for (int i = beg + t; i < end; i += 256)
        atomicAdd(&hcnt[ebuf[i].y - node0], 1);
    __syncthreads();
    int lane = t & 63, wid = t >> 6;
    int v = (t < 128) ? hcnt[t] : 0;
    int x = v;
    #pragma unroll
    for (int off = 1; off < 64; off <<= 1) {
        int y = __shfl_up(x, off, 64);
        if (lane >= off) x += y;
    }
    if (lane == 63) wends[wid] = x;
    __syncthreads();
    int excl = x - v + ((wid == 1) ? wends[0] : 0);
    if (t < 128) {
        hcur[t] = excl;
        if (t < nnode) row_ptr[node0 + t] = beg + excl;
    }
    __syncthreads();
    for (int i = beg + t; i < end; i += 256) {
        int2 e = ebuf[i];
        int p = atomicAdd(&hcur[e.y - node0], 1);
        csr[(size_t)beg + p]    = e.x;
        csrdst[(size_t)beg + p] = e.y;
    }
}

// ---- GAT layer 1 aggregation in INPUT space; U=8 edge batches per half.
__global__ __launch_bounds__(256) void gat1_agg(
    const int* __restrict__ row_ptr, const int* __restrict__ csr,
    const float* __restrict__ x,
    const float* __restrict__ a_s1, const float* __restrict__ a_d1,
    float* __restrict__ agg, float* __restrict__ ssum, int N)
{
    int gid = blockIdx.x * blockDim.x + threadIdx.x;
    int node = gid >> 6;
    if (node >= N) return;
    int lane = threadIdx.x & 63;
    int half = lane >> 5;
    int sl   = lane & 31;
    int h = sl >> 2, c = sl & 3;
    float adh = a_d1[(size_t)node * 8 + h];

    float aggv = 0.f, sv = 0.f;
    int beg = row_ptr[node], end = row_ptr[node + 1];
    constexpr int U = 8;
    for (int base = beg; base < end; base += 2 * U) {
        int   idx[U];
        float msk[U];
        #pragma unroll
        for (int u = 0; u < U; ++u) {
            int t = base + 2 * u + half;
            msk[u] = (t < end) ? 1.f : 0.f;
            idx[u] = csr[t < end ? t : (end - 1)];
        }
        float xv[U], av[U];
        #pragma unroll
        for (int u = 0; u < U; ++u) xv[u] = x[(size_t)idx[u] * 4 + c];
        #pragma unroll
        for (int u = 0; u < U; ++u) av[u] = a_s1[(size_t)idx[u] * 8 + h];
        #pragma unroll
        for (int u = 0; u < U; ++u) {
            float ev = av[u] + adh;
            ev = ev > 0.f ? ev : 0.2f * ev;
            float p = __expf(ev) * msk[u];
            sv   += p;
            aggv += p * xv[u];
        }
    }
    aggv += __shfl_xor(aggv, 32);
    sv   += __shfl_xor(sv, 32);
    if (lane < 32) {
        agg[(size_t)node * 32 + lane] = aggv;
        if (c == 0) ssum[(size_t)node * 8 + h] = sv;
    }
}

// ---- h[n] = ELU((agg/s) @ W1_head + b1), fp16 out + fused layer-2 dots.
__global__ __launch_bounds__(256) void h_kernel(
    const float* __restrict__ agg, const float* __restrict__ ssum,
    const float4* __restrict__ w1t, const float* __restrict__ b1,
    const float2* __restrict__ wa2t,
    __half* __restrict__ h2buf, float* __restrict__ a2s, float* __restrict__ a2d, int N)
{
    __shared__ float4 w1s[480];
    __shared__ float2 wa2s[480];
    __shared__ float  b1s[480];
    int t = threadIdx.x;
    for (int i = t; i < 480; i += 256) {
        w1s[i]  = w1t[i];
        wa2s[i] = wa2t[i];
        b1s[i]  = b1[i];
    }
    __syncthreads();

    int node = blockIdx.x * 4 + (t >> 6);
    if (node >= N) return;
    int lane = t & 63;
    bool act = lane < 60;

    float psrc = 0.f, pdst = 0.f;
    #pragma unroll
    for (int h = 0; h < 8; ++h) {
        float4 ag  = *(const float4*)(agg + (size_t)node * 32 + h * 4);  // uniform
        float  inv = 1.f / (ssum[(size_t)node * 8 + h] + 1e-16f);        // uniform
        if (act) {
            int col = h * 60 + lane;
            float4 w  = w1s[col];
            float raw = ag.x * w.x + ag.y * w.y + ag.z * w.z + ag.w * w.w;
            float v   = raw * inv + b1s[col];
            float o   = v > 0.f ? v : (__expf(v) - 1.f);
            h2buf[(size_t)node * 480 + col] = __float2half(o);
            float2 wz = wa2s[col];
            psrc += o * wz.x;
            pdst += o * wz.y;
        }
    }
    #pragma unroll
    for (int off = 32; off; off >>= 1) {
        psrc += __shfl_xor(psrc, off);
        pdst += __shfl_xor(pdst, off);
    }
    if (lane == 0) { a2s[node] = psrc; a2d[node] = pdst; }
}

// ---- p2: p[e] = exp(leaky(a_s2[csr[e]] + a_d2[csrdst[e]])), edge-parallel
__global__ __launch_bounds__(256) void p2_kernel(
    const int* __restrict__ csr, const int* __restrict__ csrdst,
    const float* __restrict__ a_s2, const float* __restrict__ a_d2,
    float* __restrict__ pbuf2, int EP)
{
    int i = (blockIdx.x * 256 + threadIdx.x) * 4;
    if (i + 3 < EP) {
        int4 s4 = *(const int4*)(csr + i);
        int4 d4 = *(const int4*)(csrdst + i);
        float e0 = a_s2[s4.x] + a_d2[d4.x];
        float e1 = a_s2[s4.y] + a_d2[d4.y];
        float e2 = a_s2[s4.z] + a_d2[d4.z];
        float e3 = a_s2[s4.w] + a_d2[d4.w];
        float4 o;
        o.x = __expf(fmaxf(e0, 0.2f * e0));
        o.y = __expf(fmaxf(e1, 0.2f * e1));
        o.z = __expf(fmaxf(e2, 0.2f * e2));
        o.w = __expf(fmaxf(e3, 0.2f * e3));
        *(float4*)(pbuf2 + i) = o;
    } else {
        for (int u = 0; u < 4; ++u) {
            int e = i + u;
            if (e < EP) {
                float ev = a_s2[csr[e]] + a_d2[csrdst[e]];
                pbuf2[e] = __expf(fmaxf(ev, 0.2f * ev));
            }
        }
    }
}

// ---- xh2h[N,96] = h2[N,480] @ W2[480,96] via MFMA fp16 (f32 accum).
__global__ __launch_bounds__(256) void gemm2_mfma(
    const __half* __restrict__ h2, const __half* __restrict__ w2t,
    __half* __restrict__ xh2h, int N)
{
    int wave = threadIdx.x >> 6;
    int lane = threadIdx.x & 63;
    int m0 = blockIdx.x * 64 + wave * 16;
    int ra   = lane & 15;
    int kgrp = lane >> 4;
    int m = m0 + ra;  if (m > N - 1) m = N - 1;   // clamp: OOB rows duplicate N-1

    floatx4 acc[6];
    #pragma unroll
    for (int n = 0; n < 6; ++n) acc[n] = (floatx4){0.f, 0.f, 0.f, 0.f};

    const _Float16* arow = (const _Float16*)(h2 + (size_t)m * 480);
    const _Float16* wt   = (const _Float16*)w2t;
    for (int k0 = 0; k0 < 480; k0 += 32) {
        half8 af = *(const half8*)(arow + k0 + kgrp * 8);
        #pragma unroll
        for (int n = 0; n < 6; ++n) {
            half8 bf = *(const half8*)(wt + (size_t)(n * 16 + ra) * 480 + k0 + kgrp * 8);
            acc[n] = __builtin_amdgcn_mfma_f32_16x16x32_f16(af, bf, acc[n], 0, 0, 0);
        }
    }
    #pragma unroll
    for (int n = 0; n < 6; ++n) {
        int c = n * 16 + ra;
        #pragma unroll
        for (int j = 0; j < 4; ++j) {
            int r = m0 + kgrp * 4 + j;
            if (r < N) xh2h[(size_t)r * 96 + c] = __float2half(acc[n][j]);
        }
    }
}

// ---- GAT layer 2: wave/node; contiguous s_load batches of csr + pbuf2
// (independent), gather + cvt + 2 FMA per edge; U=16.
__global__ __launch_bounds__(256) void gat2_fused(
    const int* __restrict__ row_ptr, const int* __restrict__ csr,
    const float* __restrict__ pbuf2,
    const __half* __restrict__ xh2h, const float* __restrict__ b2,
    float* __restrict__ out, int N)
{
    int gid = blockIdx.x * blockDim.x + threadIdx.x;
    int node = gid >> 6;
    if (node >= N) return;
    int lane = threadIdx.x & 63;
    bool act = lane < 48;
    float s = 0.f, ax = 0.f, ay = 0.f;
    int beg = __builtin_amdgcn_readfirstlane(row_ptr[node]);
    int end = __builtin_amdgcn_readfirstlane(row_ptr[node + 1]);
    constexpr int U = 16;
    for (int e0 = beg; e0 < end; e0 += U) {
        int   srcs[U];
        float pv[U];
        #pragma unroll
        for (int u = 0; u < U; ++u) {
            int t = e0 + u;  if (t > end - 1) t = end - 1;      // scalar clamp
            srcs[u] = __builtin_amdgcn_readfirstlane(csr[t]);
            float pr = __uint_as_float(
                __builtin_amdgcn_readfirstlane(__float_as_uint(pbuf2[t])));
            pv[u] = (e0 + u < end) ? pr : 0.f;                  // uniform select
        }
        __half2 gv[U];
        if (act) {
            #pragma unroll
            for (int u = 0; u < U; ++u)
                gv[u] = ((const __half2*)(xh2h + (size_t)srcs[u] * 96))[lane];
        }
        #pragma unroll
        for (int u = 0; u < U; ++u) {
            s += pv[u];
            if (act) {
                float2 fg = __half22float2(gv[u]);
                ax += pv[u] * fg.x;
                ay += pv[u] * fg.y;
            }
        }
    }
    float inv = 1.f / (s + 1e-16f);
    if (act) {
        out[(size_t)node * 96 + 2 * lane]     = ax * inv + b2[2 * lane];
        out[(size_t)node * 96 + 2 * lane + 1] = ay * inv + b2[2 * lane + 1];
    }
}

extern "C" void kernel_launch(void* const* d_in, const int* in_sizes, int n_in,
                              void* d_out, int out_size, void* d_ws, size_t ws_size,
                              hipStream_t stream)
{
    const float* x   = (const float*)d_in[0];
    const int*   ei  = (const int*)  d_in[1];
    const float* W1  = (const float*)d_in[2];
    const float* as1 = (const float*)d_in[3];
    const float* ad1 = (const float*)d_in[4];
    const float* b1  = (const float*)d_in[5];
    const float* W2  = (const float*)d_in[6];
    const float* as2 = (const float*)d_in[7];
    const float* ad2 = (const float*)d_in[8];
    const float* b2  = (const float*)d_in[9];
    float* out = (float*)d_out;

    int N  = in_sizes[0] / 4;   // 50000
    int E  = in_sizes[1] / 2;   // 800000
    int EP = E + N;
    int NBUK  = (N + 127) >> BSH;           // 391
    int NW2T  = (96 * 480 + 255) / 256;     // 180
    int NA1   = (N + 255) / 256;            // 196
    int NBK_H = (EP + 2047) / 2048;         // 416
    int NBK_M = (EP + 4095) / 4096;         // multisplit blocks (U=16)
    int NSETUP = 1 + NW2T + NA1 + NBK_H;

    float* f = (float*)d_ws;
    float* a_s1  = f;  f += (size_t)N * 8;
    float* a_d1  = f;  f += (size_t)N * 8;
    float* agg   = f;  f += (size_t)N * 32;
    float* ssum  = f;  f += (size_t)N * 8;
    float* a_s2  = f;  f += N;
    float* a_d2  = f;  f += N;
    float4* w1t  = (float4*)f;  f += 480 * 4;
    float2* wa2t = (float2*)f;  f += 480 * 2;
    __half* h2buf = (__half*)f;
    __half* hp   = h2buf + (size_t)N * 480;
    __half* xh2h = hp;   hp += (size_t)N * 96;
    __half* w2t  = hp;   hp += 96 * 480;
    int2* ebuf   = (int2*)hp;
    int* ip      = (int*)(ebuf + EP);
    int* row_ptr = ip;  ip += N + 1;
    int* bcnt    = ip;  ip += MAXBUK;
    int* boff    = ip;  ip += MAXBUK + 1;
    int* bcursor = ip;  ip += MAXBUK;
    int* csr     = ip;  ip += EP;
    int* csrdst  = ip;  ip += EP;
    float* pbuf2 = (float*)ip;  ip += EP;

    size_t needed = (size_t)((char*)ip - (char*)d_ws);
    if (needed > ws_size) return;  // loud failure if scratch too small

    zero_bcnt<<<1, MAXBUK, 0, stream>>>(bcnt);
    setup_kernel<<<NSETUP, 256, 0, stream>>>(
        W1, as1, ad1, W2, as2, ad2, x, ei, E, N,
        w1t, wa2t, w2t, a_s1, a_d1, bcnt, NW2T, NA1);
    bucket_scan<<<1, 512, 0, stream>>>(bcnt, NBUK, boff, bcursor, row_ptr, N);
    multisplit<<<NBK_M, 256, 0, stream>>>(ei, E, N, bcursor, ebuf);
    csrfill2<<<NBUK, 256, 0, stream>>>(ebuf, boff, row_ptr, csr, csrdst, N);
    gat1_agg<<<(N * 64 + 255) / 256, 256, 0, stream>>>(
        row_ptr, csr, x, a_s1, a_d1, agg, ssum, N);
    h_kernel<<<(N + 3) / 4, 256, 0, stream>>>(
        agg, ssum, w1t, b1, wa2t, h2buf, a_s2, a_d2, N);
    p2_kernel<<<(EP + 1023) / 1024, 256, 0, stream>>>(
        csr, csrdst, a_s2, a_d2, pbuf2, EP);
    gemm2_mfma<<<(N + 63) / 64, 256, 0, stream>>>(h2buf, w2t, xh2h, N);
    gat2_fused<<<(N * 64 + 255) / 256, 256, 0, stream>>>(
        row_ptr, csr, pbuf2, xh2h, b2, out, N);
}

// Round 20
// 174.380 us; speedup vs baseline: 2.2380x; 1.0801x over previous
//
#include <hip/hip_runtime.h>
#include <hip/hip_bf16.h>
#include <hip/hip_fp16.h>
#include <cstdint>
#include <cstddef>

// ---------------------------------------------------------------------------
// FeatureExtractorGAT, round 20.
// Single change vs R19 (188 us): h_kernel FUSED into gat1_agg (gat1_agg_h).
// The wave that aggregates a node already ends with agg[32]/ssum[8] in its
// lanes; park them in per-wave LDS and run the h-phase (ELU + h2buf fp16
// write + layer-2 attention dots) in the same wave. Deletes: h_kernel
// dispatch, the 16 MB agg/ssum global round trip, and those buffers.
// Table staging (w1t/wa2t/b1, 13.4 KB/block) moves here - same cost h_kernel
// already paid. Everything else byte-identical to R19.
// ---------------------------------------------------------------------------

typedef _Float16 half8 __attribute__((ext_vector_type(8)));
typedef float floatx4 __attribute__((ext_vector_type(4)));

constexpr int BSH = 7;            // 128 nodes per bucket
constexpr int MAXBUK = 512;       // supports N <= 65536

__global__ void zero_bcnt(int* __restrict__ bcnt)
{
    bcnt[threadIdx.x] = 0;        // MAXBUK = 512 = blockDim
}

// ---- fused setup: block 0 = prep(w1t,wa2t); [1,1+NW2T) = w2t;
// [A1_0, A1_0+NA1) = a1 (self-computed wa1 in LDS); [H0, ...) = bucket_hist.
__global__ __launch_bounds__(256) void setup_kernel(
    const float* __restrict__ W1,
    const float* __restrict__ as1, const float* __restrict__ ad1,
    const float* __restrict__ W2,
    const float* __restrict__ as2, const float* __restrict__ ad2,
    const float* __restrict__ x, const int* __restrict__ ei,
    int E, int N,
    float4* __restrict__ w1t, float2* __restrict__ wa2t,
    __half* __restrict__ w2t,
    float* __restrict__ a_s1, float* __restrict__ a_d1,
    int* __restrict__ bcnt,
    int NW2T, int NA1)
{
    __shared__ int   lcnt[MAXBUK];
    __shared__ float wa1s[64];
    int b = blockIdx.x;
    int t = threadIdx.x;
    int A1_0 = 1 + NW2T;
    int H0   = A1_0 + NA1;

    if (b == 0) {
        for (int i = t; i < 480; i += 256) {
            float accs = 0.f, accd = 0.f;
            #pragma unroll 4
            for (int c = 0; c < 96; ++c) {
                float w = W2[i * 96 + c];
                accs += w * as2[c];
                accd += w * ad2[c];
            }
            wa2t[i] = make_float2(accs, accd);
            w1t[i]  = make_float4(W1[i], W1[480 + i], W1[960 + i], W1[1440 + i]);
        }
    } else if (b < A1_0) {
        int idx = (b - 1) * 256 + t;
        if (idx < 96 * 480) {
            int n = idx / 480, k = idx - n * 480;
            w2t[idx] = __float2half(W2[k * 96 + n]);
        }
    } else if (b < H0) {
        if (t < 32) {
            int k = t >> 3, h = t & 7;
            float accs = 0.f, accd = 0.f;
            for (int c = 0; c < 60; ++c) {
                float w = W1[k * 480 + h * 60 + c];
                accs += w * as1[h * 60 + c];
                accd += w * ad1[h * 60 + c];
            }
            wa1s[k * 8 + h]      = accs;
            wa1s[32 + k * 8 + h] = accd;
        }
        __syncthreads();
        int n = (b - A1_0) * 256 + t;
        if (n < N) {
            float4 xv = *(const float4*)(x + (size_t)n * 4);
            #pragma unroll
            for (int h = 0; h < 8; ++h) {
                float as = xv.x * wa1s[h] + xv.y * wa1s[8 + h]
                         + xv.z * wa1s[16 + h] + xv.w * wa1s[24 + h];
                float ad = xv.x * wa1s[32 + h] + xv.y * wa1s[40 + h]
                         + xv.z * wa1s[48 + h] + xv.w * wa1s[56 + h];
                a_s1[n * 8 + h] = as;
                a_d1[n * 8 + h] = ad;
            }
        }
    } else {
        int nbuk = (N + 127) >> BSH;
        for (int i = t; i < nbuk; i += 256) lcnt[i] = 0;
        __syncthreads();
        #pragma unroll
        for (int u = 0; u < 8; ++u) {
            int e = (b - H0) * 2048 + u * 256 + t;
            if (e < E + N) {
                int d = (e < E) ? ei[E + e] : (e - E);
                atomicAdd(&lcnt[d >> BSH], 1);
            }
        }
        __syncthreads();
        for (int i = t; i < nbuk; i += 256)
            if (lcnt[i]) atomicAdd(&bcnt[i], lcnt[i]);
    }
}

// ---- CSR build pass 2: scan bucket counts (1 block, 512 thr)
__global__ __launch_bounds__(512) void bucket_scan(const int* __restrict__ bcnt, int nbuk,
                                                   int* __restrict__ boff,
                                                   int* __restrict__ bcursor,
                                                   int* __restrict__ row_ptr, int N)
{
    __shared__ int wsum[8];
    int t = threadIdx.x, lane = t & 63, wid = t >> 6;
    int v = (t < nbuk) ? bcnt[t] : 0;
    int x = v;
    #pragma unroll
    for (int off = 1; off < 64; off <<= 1) {
        int y = __shfl_up(x, off, 64);
        if (lane >= off) x += y;
    }
    if (lane == 63) wsum[wid] = x;
    __syncthreads();
    if (wid == 0) {
        int wv = (lane < 8) ? wsum[lane] : 0;
        #pragma unroll
        for (int off = 1; off < 8; off <<= 1) {
            int y = __shfl_up(wv, off, 64);
            if (lane >= off) wv += y;
        }
        if (lane < 8) wsum[lane] = wv;
    }
    __syncthreads();
    int excl = (wid ? wsum[wid - 1] : 0) + x - v;
    if (t < nbuk) { boff[t] = excl; bcursor[t] = excl; }
    if (t == nbuk - 1) { boff[nbuk] = excl + v; row_ptr[N] = excl + v; }
}

// ---- CSR build pass 3: multisplit (src,dst) pairs into bucket regions.
__global__ __launch_bounds__(256) void multisplit(const int* __restrict__ ei, int E, int N,
                                                  int* __restrict__ bcursor,
                                                  int2* __restrict__ ebuf)
{
    __shared__ int lcnt[MAXBUK];
    __shared__ int lbase[MAXBUK];
    int t = threadIdx.x;
    int nbuk = (N + 127) >> BSH;
    for (int b = t; b < nbuk; b += 256) lcnt[b] = 0;
    __syncthreads();
    constexpr int U = 16;
    int ss[U], dd[U], rk[U];
    bool ok[U];
    #pragma unroll
    for (int u = 0; u < U; ++u) {
        int e = blockIdx.x * (256 * U) + u * 256 + t;
        ok[u] = e < E + N;
        if (ok[u]) {
            if (e < E) { ss[u] = ei[e]; dd[u] = ei[E + e]; } else { ss[u] = dd[u] = e - E; }
            rk[u] = atomicAdd(&lcnt[dd[u] >> BSH], 1);
        }
    }
    __syncthreads();
    for (int b = t; b < nbuk; b += 256)
        lbase[b] = lcnt[b] ? atomicAdd(&bcursor[b], lcnt[b]) : 0;
    __syncthreads();
    #pragma unroll
    for (int u = 0; u < U; ++u)
        if (ok[u]) ebuf[(size_t)lbase[dd[u] >> BSH] + rk[u]] = make_int2(ss[u], dd[u]);
}

// ---- CSR build pass 4: one block per bucket; cursors in LDS; writes
// csr AND csrdst (dst companion, needed by p2_kernel).
__global__ __launch_bounds__(256) void csrfill2(const int2* __restrict__ ebuf,
                                                const int* __restrict__ boff,
                                                int* __restrict__ row_ptr,
                                                int* __restrict__ csr,
                                                int* __restrict__ csrdst, int N)
{
    int b = blockIdx.x;
    int node0 = b << BSH;
    int nnode = N - node0;  if (nnode > 128) nnode = 128;
    int beg = boff[b], end = boff[b + 1];
    __shared__ int hcnt[128], hcur[128];
    __shared__ int wends[4];
    int t = threadIdx.x;
    if (t < 128) hcnt[t] = 0;
    __syncthreads();
    for (int i = beg + t; i < end; i += 256)
        atomicAdd(&hcnt[ebuf[i].y - node0], 1);
    __syncthreads();
    int lane = t & 63, wid = t >> 6;
    int v = (t < 128) ? hcnt[t] : 0;
    int x = v;
    #pragma unroll
    for (int off = 1; off < 64; off <<= 1) {
        int y = __shfl_up(x, off, 64);
        if (lane >= off) x += y;
    }
    if (lane == 63) wends[wid] = x;
    __syncthreads();
    int excl = x - v + ((wid == 1) ? wends[0] : 0);
    if (t < 128) {
        hcur[t] = excl;
        if (t < nnode) row_ptr[node0 + t] = beg + excl;
    }
    __syncthreads();
    for (int i = beg + t; i < end; i += 256) {
        int2 e = ebuf[i];
        int p = atomicAdd(&hcur[e.y - node0], 1);
        csr[(size_t)beg + p]    = e.x;
        csrdst[(size_t)beg + p] = e.y;
    }
}

// ---- GAT layer 1: aggregation (input space, U=8) + h-phase, fused.
// Block = 256 thr = 4 waves = 4 nodes. Tables staged in LDS per block.
// Edge phase: lane = (half, h=sl>>2, c=sl&3). After reduce, agg/ssum parked
// in per-wave LDS; h-phase: lane l<60 handles cols h*60+l (wave-contiguous).
__global__ __launch_bounds__(256) void gat1_agg_h(
    const int* __restrict__ row_ptr, const int* __restrict__ csr,
    const float* __restrict__ x,
    const float* __restrict__ a_s1, const float* __restrict__ a_d1,
    const float4* __restrict__ w1t, const float* __restrict__ b1,
    const float2* __restrict__ wa2t,
    __half* __restrict__ h2buf, float* __restrict__ a2s, float* __restrict__ a2d, int N)
{
    __shared__ float4 w1s[480];
    __shared__ float2 wa2s[480];
    __shared__ float  b1s[480];
    __shared__ float  aggL[4][32];
    __shared__ float  ssumL[4][8];
    int t = threadIdx.x;
    for (int i = t; i < 480; i += 256) {
        w1s[i]  = w1t[i];
        wa2s[i] = wa2t[i];
        b1s[i]  = b1[i];
    }
    __syncthreads();   // single block-wide barrier (tables ready)

    int wv   = t >> 6;
    int node = blockIdx.x * 4 + wv;
    if (node >= N) return;
    int lane = t & 63;

    // ---- edge phase ----
    {
        int half = lane >> 5;
        int sl   = lane & 31;
        int h = sl >> 2, c = sl & 3;
        float adh = a_d1[(size_t)node * 8 + h];
        float aggv = 0.f, sv = 0.f;
        int beg = row_ptr[node], end = row_ptr[node + 1];
        constexpr int U = 8;
        for (int base = beg; base < end; base += 2 * U) {
            int   idx[U];
            float msk[U];
            #pragma unroll
            for (int u = 0; u < U; ++u) {
                int tt = base + 2 * u + half;
                msk[u] = (tt < end) ? 1.f : 0.f;
                idx[u] = csr[tt < end ? tt : (end - 1)];
            }
            float xv[U], av[U];
            #pragma unroll
            for (int u = 0; u < U; ++u) xv[u] = x[(size_t)idx[u] * 4 + c];
            #pragma unroll
            for (int u = 0; u < U; ++u) av[u] = a_s1[(size_t)idx[u] * 8 + h];
            #pragma unroll
            for (int u = 0; u < U; ++u) {
                float ev = av[u] + adh;
                ev = ev > 0.f ? ev : 0.2f * ev;
                float p = __expf(ev) * msk[u];
                sv   += p;
                aggv += p * xv[u];
            }
        }
        aggv += __shfl_xor(aggv, 32);
        sv   += __shfl_xor(sv, 32);
        if (lane < 32) {
            aggL[wv][lane] = aggv;
            if (c == 0) ssumL[wv][h] = sv;
        }
    }
    // same-wave LDS write->read: ordered by lgkmcnt, no barrier needed

    // ---- h phase ----
    bool act = lane < 60;
    float psrc = 0.f, pdst = 0.f;
    #pragma unroll
    for (int h = 0; h < 8; ++h) {
        float ag0 = aggL[wv][h * 4 + 0];
        float ag1 = aggL[wv][h * 4 + 1];
        float ag2 = aggL[wv][h * 4 + 2];
        float ag3 = aggL[wv][h * 4 + 3];
        float inv = 1.f / (ssumL[wv][h] + 1e-16f);
        if (act) {
            int col = h * 60 + lane;
            float4 w  = w1s[col];
            float raw = ag0 * w.x + ag1 * w.y + ag2 * w.z + ag3 * w.w;
            float v   = raw * inv + b1s[col];
            float o   = v > 0.f ? v : (__expf(v) - 1.f);
            h2buf[(size_t)node * 480 + col] = __float2half(o);
            float2 wz = wa2s[col];
            psrc += o * wz.x;
            pdst += o * wz.y;
        }
    }
    #pragma unroll
    for (int off = 32; off; off >>= 1) {
        psrc += __shfl_xor(psrc, off);
        pdst += __shfl_xor(pdst, off);
    }
    if (lane == 0) { a2s[node] = psrc; a2d[node] = pdst; }
}

// ---- p2: p[e] = exp(leaky(a_s2[csr[e]] + a_d2[csrdst[e]])), edge-parallel
__global__ __launch_bounds__(256) void p2_kernel(
    const int* __restrict__ csr, const int* __restrict__ csrdst,
    const float* __restrict__ a_s2, const float* __restrict__ a_d2,
    float* __restrict__ pbuf2, int EP)
{
    int i = (blockIdx.x * 256 + threadIdx.x) * 4;
    if (i + 3 < EP) {
        int4 s4 = *(const int4*)(csr + i);
        int4 d4 = *(const int4*)(csrdst + i);
        float e0 = a_s2[s4.x] + a_d2[d4.x];
        float e1 = a_s2[s4.y] + a_d2[d4.y];
        float e2 = a_s2[s4.z] + a_d2[d4.z];
        float e3 = a_s2[s4.w] + a_d2[d4.w];
        float4 o;
        o.x = __expf(fmaxf(e0, 0.2f * e0));
        o.y = __expf(fmaxf(e1, 0.2f * e1));
        o.z = __expf(fmaxf(e2, 0.2f * e2));
        o.w = __expf(fmaxf(e3, 0.2f * e3));
        *(float4*)(pbuf2 + i) = o;
    } else {
        for (int u = 0; u < 4; ++u) {
            int e = i + u;
            if (e < EP) {
                float ev = a_s2[csr[e]] + a_d2[csrdst[e]];
                pbuf2[e] = __expf(fmaxf(ev, 0.2f * ev));
            }
        }
    }
}

// ---- xh2h[N,96] = h2[N,480] @ W2[480,96] via MFMA fp16 (f32 accum).
__global__ __launch_bounds__(256) void gemm2_mfma(
    const __half* __restrict__ h2, const __half* __restrict__ w2t,
    __half* __restrict__ xh2h, int N)
{
    int wave = threadIdx.x >> 6;
    int lane = threadIdx.x & 63;
    int m0 = blockIdx.x * 64 + wave * 16;
    int ra   = lane & 15;
    int kgrp = lane >> 4;
    int m = m0 + ra;  if (m > N - 1) m = N - 1;   // clamp: OOB rows duplicate N-1

    floatx4 acc[6];
    #pragma unroll
    for (int n = 0; n < 6; ++n) acc[n] = (floatx4){0.f, 0.f, 0.f, 0.f};

    const _Float16* arow = (const _Float16*)(h2 + (size_t)m * 480);
    const _Float16* wt   = (const _Float16*)w2t;
    for (int k0 = 0; k0 < 480; k0 += 32) {
        half8 af = *(const half8*)(arow + k0 + kgrp * 8);
        #pragma unroll
        for (int n = 0; n < 6; ++n) {
            half8 bf = *(const half8*)(wt + (size_t)(n * 16 + ra) * 480 + k0 + kgrp * 8);
            acc[n] = __builtin_amdgcn_mfma_f32_16x16x32_f16(af, bf, acc[n], 0, 0, 0);
        }
    }
    #pragma unroll
    for (int n = 0; n < 6; ++n) {
        int c = n * 16 + ra;
        #pragma unroll
        for (int j = 0; j < 4; ++j) {
            int r = m0 + kgrp * 4 + j;
            if (r < N) xh2h[(size_t)r * 96 + c] = __float2half(acc[n][j]);
        }
    }
}

// ---- GAT layer 2: wave/node; contiguous s_load batches of csr + pbuf2
// (independent), gather + cvt + 2 FMA per edge; U=16.
__global__ __launch_bounds__(256) void gat2_fused(
    const int* __restrict__ row_ptr, const int* __restrict__ csr,
    const float* __restrict__ pbuf2,
    const __half* __restrict__ xh2h, const float* __restrict__ b2,
    float* __restrict__ out, int N)
{
    int gid = blockIdx.x * blockDim.x + threadIdx.x;
    int node = gid >> 6;
    if (node >= N) return;
    int lane = threadIdx.x & 63;
    bool act = lane < 48;
    float s = 0.f, ax = 0.f, ay = 0.f;
    int beg = __builtin_amdgcn_readfirstlane(row_ptr[node]);
    int end = __builtin_amdgcn_readfirstlane(row_ptr[node + 1]);
    constexpr int U = 16;
    for (int e0 = beg; e0 < end; e0 += U) {
        int   srcs[U];
        float pv[U];
        #pragma unroll
        for (int u = 0; u < U; ++u) {
            int t = e0 + u;  if (t > end - 1) t = end - 1;      // scalar clamp
            srcs[u] = __builtin_amdgcn_readfirstlane(csr[t]);
            float pr = __uint_as_float(
                __builtin_amdgcn_readfirstlane(__float_as_uint(pbuf2[t])));
            pv[u] = (e0 + u < end) ? pr : 0.f;                  // uniform select
        }
        __half2 gv[U];
        if (act) {
            #pragma unroll
            for (int u = 0; u < U; ++u)
                gv[u] = ((const __half2*)(xh2h + (size_t)srcs[u] * 96))[lane];
        }
        #pragma unroll
        for (int u = 0; u < U; ++u) {
            s += pv[u];
            if (act) {
                float2 fg = __half22float2(gv[u]);
                ax += pv[u] * fg.x;
                ay += pv[u] * fg.y;
            }
        }
    }
    float inv = 1.f / (s + 1e-16f);
    if (act) {
        out[(size_t)node * 96 + 2 * lane]     = ax * inv + b2[2 * lane];
        out[(size_t)node * 96 + 2 * lane + 1] = ay * inv + b2[2 * lane + 1];
    }
}

extern "C" void kernel_launch(void* const* d_in, const int* in_sizes, int n_in,
                              void* d_out, int out_size, void* d_ws, size_t ws_size,
                              hipStream_t stream)
{
    const float* x   = (const float*)d_in[0];
    const int*   ei  = (const int*)  d_in[1];
    const float* W1  = (const float*)d_in[2];
    const float* as1 = (const float*)d_in[3];
    const float* ad1 = (const float*)d_in[4];
    const float* b1  = (const float*)d_in[5];
    const float* W2  = (const float*)d_in[6];
    const float* as2 = (const float*)d_in[7];
    const float* ad2 = (const float*)d_in[8];
    const float* b2  = (const float*)d_in[9];
    float* out = (float*)d_out;

    int N  = in_sizes[0] / 4;   // 50000
    int E  = in_sizes[1] / 2;   // 800000
    int EP = E + N;
    int NBUK  = (N + 127) >> BSH;           // 391
    int NW2T  = (96 * 480 + 255) / 256;     // 180
    int NA1   = (N + 255) / 256;            // 196
    int NBK_H = (EP + 2047) / 2048;         // 416
    int NBK_M = (EP + 4095) / 4096;         // multisplit blocks (U=16)
    int NSETUP = 1 + NW2T + NA1 + NBK_H;

    float* f = (float*)d_ws;
    float* a_s1  = f;  f += (size_t)N * 8;
    float* a_d1  = f;  f += (size_t)N * 8;
    float* a_s2  = f;  f += N;
    float* a_d2  = f;  f += N;
    float4* w1t  = (float4*)f;  f += 480 * 4;
    float2* wa2t = (float2*)f;  f += 480 * 2;
    __half* h2buf = (__half*)f;
    __half* hp   = h2buf + (size_t)N * 480;
    __half* xh2h = hp;   hp += (size_t)N * 96;
    __half* w2t  = hp;   hp += 96 * 480;
    int2* ebuf   = (int2*)hp;
    int* ip      = (int*)(ebuf + EP);
    int* row_ptr = ip;  ip += N + 1;
    int* bcnt    = ip;  ip += MAXBUK;
    int* boff    = ip;  ip += MAXBUK + 1;
    int* bcursor = ip;  ip += MAXBUK;
    int* csr     = ip;  ip += EP;
    int* csrdst  = ip;  ip += EP;
    float* pbuf2 = (float*)ip;  ip += EP;

    size_t needed = (size_t)((char*)ip - (char*)d_ws);
    if (needed > ws_size) return;  // loud failure if scratch too small

    zero_bcnt<<<1, MAXBUK, 0, stream>>>(bcnt);
    setup_kernel<<<NSETUP, 256, 0, stream>>>(
        W1, as1, ad1, W2, as2, ad2, x, ei, E, N,
        w1t, wa2t, w2t, a_s1, a_d1, bcnt, NW2T, NA1);
    bucket_scan<<<1, 512, 0, stream>>>(bcnt, NBUK, boff, bcursor, row_ptr, N);
    multisplit<<<NBK_M, 256, 0, stream>>>(ei, E, N, bcursor, ebuf);
    csrfill2<<<NBUK, 256, 0, stream>>>(ebuf, boff, row_ptr, csr, csrdst, N);
    gat1_agg_h<<<(N + 3) / 4, 256, 0, stream>>>(
        row_ptr, csr, x, a_s1, a_d1, w1t, b1, wa2t, h2buf, a_s2, a_d2, N);
    p2_kernel<<<(EP + 1023) / 1024, 256, 0, stream>>>(
        csr, csrdst, a_s2, a_d2, pbuf2, EP);
    gemm2_mfma<<<(N + 63) / 64, 256, 0, stream>>>(h2buf, w2t, xh2h, N);
    gat2_fused<<<(N * 64 + 255) / 256, 256, 0, stream>>>(
        row_ptr, csr, pbuf2, xh2h, b2, out, N);
}

// Round 21
// 167.972 us; speedup vs baseline: 2.3234x; 1.0381x over previous
//
#include <hip/hip_runtime.h>
#include <hip/hip_bf16.h>
#include <hip/hip_fp16.h>
#include <cstdint>
#include <cstddef>

// ---------------------------------------------------------------------------
// FeatureExtractorGAT, round 21.
// Single change vs R20 (174 us; gat1_agg_h 55 us @ VALUBusy 91% ->
// VALU-instruction-bound; old (h,c) lane map computed each exp 4x and issued
// 24 scalar-gather VMEM instrs per 16 edges):
//   gat1_agg_h edge phase remapped to (edge-slot x head): lane = es*8+h,
//   8 edges in flight per wave. Per lane: 1 float4 x-row load (all 4 c),
//   1 a_s1 scalar (h-contiguous), 1 exp per (edge,h) - no duplication;
//   float4 accumulate; 3 shfl_xor (8/16/32) folds edge-slots; lanes 0-7
//   park agg/ssum in LDS. VMEM instrs/16 edges: 24 -> 6; VALU ~100 -> ~36.
// h-phase and all other kernels byte-identical to R20.
// ---------------------------------------------------------------------------

typedef _Float16 half8 __attribute__((ext_vector_type(8)));
typedef float floatx4 __attribute__((ext_vector_type(4)));

constexpr int BSH = 7;            // 128 nodes per bucket
constexpr int MAXBUK = 512;       // supports N <= 65536

__global__ void zero_bcnt(int* __restrict__ bcnt)
{
    bcnt[threadIdx.x] = 0;        // MAXBUK = 512 = blockDim
}

// ---- fused setup: block 0 = prep(w1t,wa2t); [1,1+NW2T) = w2t;
// [A1_0, A1_0+NA1) = a1 (self-computed wa1 in LDS); [H0, ...) = bucket_hist.
__global__ __launch_bounds__(256) void setup_kernel(
    const float* __restrict__ W1,
    const float* __restrict__ as1, const float* __restrict__ ad1,
    const float* __restrict__ W2,
    const float* __restrict__ as2, const float* __restrict__ ad2,
    const float* __restrict__ x, const int* __restrict__ ei,
    int E, int N,
    float4* __restrict__ w1t, float2* __restrict__ wa2t,
    __half* __restrict__ w2t,
    float* __restrict__ a_s1, float* __restrict__ a_d1,
    int* __restrict__ bcnt,
    int NW2T, int NA1)
{
    __shared__ int   lcnt[MAXBUK];
    __shared__ float wa1s[64];
    int b = blockIdx.x;
    int t = threadIdx.x;
    int A1_0 = 1 + NW2T;
    int H0   = A1_0 + NA1;

    if (b == 0) {
        for (int i = t; i < 480; i += 256) {
            float accs = 0.f, accd = 0.f;
            #pragma unroll 4
            for (int c = 0; c < 96; ++c) {
                float w = W2[i * 96 + c];
                accs += w * as2[c];
                accd += w * ad2[c];
            }
            wa2t[i] = make_float2(accs, accd);
            w1t[i]  = make_float4(W1[i], W1[480 + i], W1[960 + i], W1[1440 + i]);
        }
    } else if (b < A1_0) {
        int idx = (b - 1) * 256 + t;
        if (idx < 96 * 480) {
            int n = idx / 480, k = idx - n * 480;
            w2t[idx] = __float2half(W2[k * 96 + n]);
        }
    } else if (b < H0) {
        if (t < 32) {
            int k = t >> 3, h = t & 7;
            float accs = 0.f, accd = 0.f;
            for (int c = 0; c < 60; ++c) {
                float w = W1[k * 480 + h * 60 + c];
                accs += w * as1[h * 60 + c];
                accd += w * ad1[h * 60 + c];
            }
            wa1s[k * 8 + h]      = accs;
            wa1s[32 + k * 8 + h] = accd;
        }
        __syncthreads();
        int n = (b - A1_0) * 256 + t;
        if (n < N) {
            float4 xv = *(const float4*)(x + (size_t)n * 4);
            #pragma unroll
            for (int h = 0; h < 8; ++h) {
                float as = xv.x * wa1s[h] + xv.y * wa1s[8 + h]
                         + xv.z * wa1s[16 + h] + xv.w * wa1s[24 + h];
                float ad = xv.x * wa1s[32 + h] + xv.y * wa1s[40 + h]
                         + xv.z * wa1s[48 + h] + xv.w * wa1s[56 + h];
                a_s1[n * 8 + h] = as;
                a_d1[n * 8 + h] = ad;
            }
        }
    } else {
        int nbuk = (N + 127) >> BSH;
        for (int i = t; i < nbuk; i += 256) lcnt[i] = 0;
        __syncthreads();
        #pragma unroll
        for (int u = 0; u < 8; ++u) {
            int e = (b - H0) * 2048 + u * 256 + t;
            if (e < E + N) {
                int d = (e < E) ? ei[E + e] : (e - E);
                atomicAdd(&lcnt[d >> BSH], 1);
            }
        }
        __syncthreads();
        for (int i = t; i < nbuk; i += 256)
            if (lcnt[i]) atomicAdd(&bcnt[i], lcnt[i]);
    }
}

// ---- CSR build pass 2: scan bucket counts (1 block, 512 thr)
__global__ __launch_bounds__(512) void bucket_scan(const int* __restrict__ bcnt, int nbuk,
                                                   int* __restrict__ boff,
                                                   int* __restrict__ bcursor,
                                                   int* __restrict__ row_ptr, int N)
{
    __shared__ int wsum[8];
    int t = threadIdx.x, lane = t & 63, wid = t >> 6;
    int v = (t < nbuk) ? bcnt[t] : 0;
    int x = v;
    #pragma unroll
    for (int off = 1; off < 64; off <<= 1) {
        int y = __shfl_up(x, off, 64);
        if (lane >= off) x += y;
    }
    if (lane == 63) wsum[wid] = x;
    __syncthreads();
    if (wid == 0) {
        int wv = (lane < 8) ? wsum[lane] : 0;
        #pragma unroll
        for (int off = 1; off < 8; off <<= 1) {
            int y = __shfl_up(wv, off, 64);
            if (lane >= off) wv += y;
        }
        if (lane < 8) wsum[lane] = wv;
    }
    __syncthreads();
    int excl = (wid ? wsum[wid - 1] : 0) + x - v;
    if (t < nbuk) { boff[t] = excl; bcursor[t] = excl; }
    if (t == nbuk - 1) { boff[nbuk] = excl + v; row_ptr[N] = excl + v; }
}

// ---- CSR build pass 3: multisplit (src,dst) pairs into bucket regions.
__global__ __launch_bounds__(256) void multisplit(const int* __restrict__ ei, int E, int N,
                                                  int* __restrict__ bcursor,
                                                  int2* __restrict__ ebuf)
{
    __shared__ int lcnt[MAXBUK];
    __shared__ int lbase[MAXBUK];
    int t = threadIdx.x;
    int nbuk = (N + 127) >> BSH;
    for (int b = t; b < nbuk; b += 256) lcnt[b] = 0;
    __syncthreads();
    constexpr int U = 16;
    int ss[U], dd[U], rk[U];
    bool ok[U];
    #pragma unroll
    for (int u = 0; u < U; ++u) {
        int e = blockIdx.x * (256 * U) + u * 256 + t;
        ok[u] = e < E + N;
        if (ok[u]) {
            if (e < E) { ss[u] = ei[e]; dd[u] = ei[E + e]; } else { ss[u] = dd[u] = e - E; }
            rk[u] = atomicAdd(&lcnt[dd[u] >> BSH], 1);
        }
    }
    __syncthreads();
    for (int b = t; b < nbuk; b += 256)
        lbase[b] = lcnt[b] ? atomicAdd(&bcursor[b], lcnt[b]) : 0;
    __syncthreads();
    #pragma unroll
    for (int u = 0; u < U; ++u)
        if (ok[u]) ebuf[(size_t)lbase[dd[u] >> BSH] + rk[u]] = make_int2(ss[u], dd[u]);
}

// ---- CSR build pass 4: one block per bucket; cursors in LDS; writes
// csr AND csrdst (dst companion, needed by p2_kernel).
__global__ __launch_bounds__(256) void csrfill2(const int2* __restrict__ ebuf,
                                                const int* __restrict__ boff,
                                                int* __restrict__ row_ptr,
                                                int* __restrict__ csr,
                                                int* __restrict__ csrdst, int N)
{
    int b = blockIdx.x;
    int node0 = b << BSH;
    int nnode = N - node0;  if (nnode > 128) nnode = 128;
    int beg = boff[b], end = boff[b + 1];
    __shared__ int hcnt[128], hcur[128];
    __shared__ int wends[4];
    int t = threadIdx.x;
    if (t < 128) hcnt[t] = 0;
    __syncthreads();
    for (int i = beg + t; i < end; i += 256)
        atomicAdd(&hcnt[ebuf[i].y - node0], 1);
    __syncthreads();
    int lane = t & 63, wid = t >> 6;
    int v = (t < 128) ? hcnt[t] : 0;
    int x = v;
    #pragma unroll
    for (int off = 1; off < 64; off <<= 1) {
        int y = __shfl_up(x, off, 64);
        if (lane >= off) x += y;
    }
    if (lane == 63) wends[wid] = x;
    __syncthreads();
    int excl = x - v + ((wid == 1) ? wends[0] : 0);
    if (t < 128) {
        hcur[t] = excl;
        if (t < nnode) row_ptr[node0 + t] = beg + excl;
    }
    __syncthreads();
    for (int i = beg + t; i < end; i += 256) {
        int2 e = ebuf[i];
        int p = atomicAdd(&hcur[e.y - node0], 1);
        csr[(size_t)beg + p]    = e.x;
        csrdst[(size_t)beg + p] = e.y;
    }
}

// ---- GAT layer 1: aggregation + h-phase, fused. Block = 4 waves = 4 nodes.
// Edge phase: lane = es*8 + h (8 edge-slots x 8 heads). Per lane: 1 float4
// x-load, 1 a_s1 scalar, 1 exp; float4 accumulate; shfl_xor(8/16/32) folds
// edge-slots; lanes 0-7 park agg/ssum in per-wave LDS.
__global__ __launch_bounds__(256) void gat1_agg_h(
    const int* __restrict__ row_ptr, const int* __restrict__ csr,
    const float* __restrict__ x,
    const float* __restrict__ a_s1, const float* __restrict__ a_d1,
    const float4* __restrict__ w1t, const float* __restrict__ b1,
    const float2* __restrict__ wa2t,
    __half* __restrict__ h2buf, float* __restrict__ a2s, float* __restrict__ a2d, int N)
{
    __shared__ float4 w1s[480];
    __shared__ float2 wa2s[480];
    __shared__ float  b1s[480];
    __shared__ float  aggL[4][32];
    __shared__ float  ssumL[4][8];
    int t = threadIdx.x;
    for (int i = t; i < 480; i += 256) {
        w1s[i]  = w1t[i];
        wa2s[i] = wa2t[i];
        b1s[i]  = b1[i];
    }
    __syncthreads();   // tables ready

    int wv   = t >> 6;
    int node = blockIdx.x * 4 + wv;
    if (node >= N) return;
    int lane = t & 63;

    // ---- edge phase: lane = es*8 + h ----
    {
        int es = lane >> 3;
        int h  = lane & 7;
        float adh = a_d1[(size_t)node * 8 + h];
        float ax = 0.f, ay = 0.f, az = 0.f, aw = 0.f, sv = 0.f;
        int beg = row_ptr[node], end = row_ptr[node + 1];
        constexpr int U = 2;                 // 16 edges per iteration
        for (int base = beg; base < end; base += 8 * U) {
            int   src[U];
            float msk[U];
            #pragma unroll
            for (int u = 0; u < U; ++u) {
                int tt = base + u * 8 + es;
                msk[u] = (tt < end) ? 1.f : 0.f;
                src[u] = csr[tt < end ? tt : (end - 1)];
            }
            float4 xv[U];
            float  asv[U];
            #pragma unroll
            for (int u = 0; u < U; ++u) xv[u] = *(const float4*)(x + (size_t)src[u] * 4);
            #pragma unroll
            for (int u = 0; u < U; ++u) asv[u] = a_s1[(size_t)src[u] * 8 + h];
            #pragma unroll
            for (int u = 0; u < U; ++u) {
                float ev = asv[u] + adh;
                ev = fmaxf(ev, 0.2f * ev);
                float p = __expf(ev) * msk[u];
                sv += p;
                ax += p * xv[u].x;
                ay += p * xv[u].y;
                az += p * xv[u].z;
                aw += p * xv[u].w;
            }
        }
        #pragma unroll
        for (int off = 8; off <= 32; off <<= 1) {
            ax += __shfl_xor(ax, off);
            ay += __shfl_xor(ay, off);
            az += __shfl_xor(az, off);
            aw += __shfl_xor(aw, off);
            sv += __shfl_xor(sv, off);
        }
        if (lane < 8) {                       // es == 0 holds the totals
            aggL[wv][h * 4 + 0] = ax;
            aggL[wv][h * 4 + 1] = ay;
            aggL[wv][h * 4 + 2] = az;
            aggL[wv][h * 4 + 3] = aw;
            ssumL[wv][h] = sv;
        }
    }
    // same-wave LDS write->read: ordered by lgkmcnt, no barrier needed

    // ---- h phase ----
    bool act = lane < 60;
    float psrc = 0.f, pdst = 0.f;
    #pragma unroll
    for (int h = 0; h < 8; ++h) {
        float ag0 = aggL[wv][h * 4 + 0];
        float ag1 = aggL[wv][h * 4 + 1];
        float ag2 = aggL[wv][h * 4 + 2];
        float ag3 = aggL[wv][h * 4 + 3];
        float inv = 1.f / (ssumL[wv][h] + 1e-16f);
        if (act) {
            int col = h * 60 + lane;
            float4 w  = w1s[col];
            float raw = ag0 * w.x + ag1 * w.y + ag2 * w.z + ag3 * w.w;
            float v   = raw * inv + b1s[col];
            float o   = v > 0.f ? v : (__expf(v) - 1.f);
            h2buf[(size_t)node * 480 + col] = __float2half(o);
            float2 wz = wa2s[col];
            psrc += o * wz.x;
            pdst += o * wz.y;
        }
    }
    #pragma unroll
    for (int off = 32; off; off >>= 1) {
        psrc += __shfl_xor(psrc, off);
        pdst += __shfl_xor(pdst, off);
    }
    if (lane == 0) { a2s[node] = psrc; a2d[node] = pdst; }
}

// ---- p2: p[e] = exp(leaky(a_s2[csr[e]] + a_d2[csrdst[e]])), edge-parallel
__global__ __launch_bounds__(256) void p2_kernel(
    const int* __restrict__ csr, const int* __restrict__ csrdst,
    const float* __restrict__ a_s2, const float* __restrict__ a_d2,
    float* __restrict__ pbuf2, int EP)
{
    int i = (blockIdx.x * 256 + threadIdx.x) * 4;
    if (i + 3 < EP) {
        int4 s4 = *(const int4*)(csr + i);
        int4 d4 = *(const int4*)(csrdst + i);
        float e0 = a_s2[s4.x] + a_d2[d4.x];
        float e1 = a_s2[s4.y] + a_d2[d4.y];
        float e2 = a_s2[s4.z] + a_d2[d4.z];
        float e3 = a_s2[s4.w] + a_d2[d4.w];
        float4 o;
        o.x = __expf(fmaxf(e0, 0.2f * e0));
        o.y = __expf(fmaxf(e1, 0.2f * e1));
        o.z = __expf(fmaxf(e2, 0.2f * e2));
        o.w = __expf(fmaxf(e3, 0.2f * e3));
        *(float4*)(pbuf2 + i) = o;
    } else {
        for (int u = 0; u < 4; ++u) {
            int e = i + u;
            if (e < EP) {
                float ev = a_s2[csr[e]] + a_d2[csrdst[e]];
                pbuf2[e] = __expf(fmaxf(ev, 0.2f * ev));
            }
        }
    }
}

// ---- xh2h[N,96] = h2[N,480] @ W2[480,96] via MFMA fp16 (f32 accum).
__global__ __launch_bounds__(256) void gemm2_mfma(
    const __half* __restrict__ h2, const __half* __restrict__ w2t,
    __half* __restrict__ xh2h, int N)
{
    int wave = threadIdx.x >> 6;
    int lane = threadIdx.x & 63;
    int m0 = blockIdx.x * 64 + wave * 16;
    int ra   = lane & 15;
    int kgrp = lane >> 4;
    int m = m0 + ra;  if (m > N - 1) m = N - 1;   // clamp: OOB rows duplicate N-1

    floatx4 acc[6];
    #pragma unroll
    for (int n = 0; n < 6; ++n) acc[n] = (floatx4){0.f, 0.f, 0.f, 0.f};

    const _Float16* arow = (const _Float16*)(h2 + (size_t)m * 480);
    const _Float16* wt   = (const _Float16*)w2t;
    for (int k0 = 0; k0 < 480; k0 += 32) {
        half8 af = *(const half8*)(arow + k0 + kgrp * 8);
        #pragma unroll
        for (int n = 0; n < 6; ++n) {
            half8 bf = *(const half8*)(wt + (size_t)(n * 16 + ra) * 480 + k0 + kgrp * 8);
            acc[n] = __builtin_amdgcn_mfma_f32_16x16x32_f16(af, bf, acc[n], 0, 0, 0);
        }
    }
    #pragma unroll
    for (int n = 0; n < 6; ++n) {
        int c = n * 16 + ra;
        #pragma unroll
        for (int j = 0; j < 4; ++j) {
            int r = m0 + kgrp * 4 + j;
            if (r < N) xh2h[(size_t)r * 96 + c] = __float2half(acc[n][j]);
        }
    }
}

// ---- GAT layer 2: wave/node; contiguous s_load batches of csr + pbuf2
// (independent), gather + cvt + 2 FMA per edge; U=16.
__global__ __launch_bounds__(256) void gat2_fused(
    const int* __restrict__ row_ptr, const int* __restrict__ csr,
    const float* __restrict__ pbuf2,
    const __half* __restrict__ xh2h, const float* __restrict__ b2,
    float* __restrict__ out, int N)
{
    int gid = blockIdx.x * blockDim.x + threadIdx.x;
    int node = gid >> 6;
    if (node >= N) return;
    int lane = threadIdx.x & 63;
    bool act = lane < 48;
    float s = 0.f, ax = 0.f, ay = 0.f;
    int beg = __builtin_amdgcn_readfirstlane(row_ptr[node]);
    int end = __builtin_amdgcn_readfirstlane(row_ptr[node + 1]);
    constexpr int U = 16;
    for (int e0 = beg; e0 < end; e0 += U) {
        int   srcs[U];
        float pv[U];
        #pragma unroll
        for (int u = 0; u < U; ++u) {
            int t = e0 + u;  if (t > end - 1) t = end - 1;      // scalar clamp
            srcs[u] = __builtin_amdgcn_readfirstlane(csr[t]);
            float pr = __uint_as_float(
                __builtin_amdgcn_readfirstlane(__float_as_uint(pbuf2[t])));
            pv[u] = (e0 + u < end) ? pr : 0.f;                  // uniform select
        }
        __half2 gv[U];
        if (act) {
            #pragma unroll
            for (int u = 0; u < U; ++u)
                gv[u] = ((const __half2*)(xh2h + (size_t)srcs[u] * 96))[lane];
        }
        #pragma unroll
        for (int u = 0; u < U; ++u) {
            s += pv[u];
            if (act) {
                float2 fg = __half22float2(gv[u]);
                ax += pv[u] * fg.x;
                ay += pv[u] * fg.y;
            }
        }
    }
    float inv = 1.f / (s + 1e-16f);
    if (act) {
        out[(size_t)node * 96 + 2 * lane]     = ax * inv + b2[2 * lane];
        out[(size_t)node * 96 + 2 * lane + 1] = ay * inv + b2[2 * lane + 1];
    }
}

extern "C" void kernel_launch(void* const* d_in, const int* in_sizes, int n_in,
                              void* d_out, int out_size, void* d_ws, size_t ws_size,
                              hipStream_t stream)
{
    const float* x   = (const float*)d_in[0];
    const int*   ei  = (const int*)  d_in[1];
    const float* W1  = (const float*)d_in[2];
    const float* as1 = (const float*)d_in[3];
    const float* ad1 = (const float*)d_in[4];
    const float* b1  = (const float*)d_in[5];
    const float* W2  = (const float*)d_in[6];
    const float* as2 = (const float*)d_in[7];
    const float* ad2 = (const float*)d_in[8];
    const float* b2  = (const float*)d_in[9];
    float* out = (float*)d_out;

    int N  = in_sizes[0] / 4;   // 50000
    int E  = in_sizes[1] / 2;   // 800000
    int EP = E + N;
    int NBUK  = (N + 127) >> BSH;           // 391
    int NW2T  = (96 * 480 + 255) / 256;     // 180
    int NA1   = (N + 255) / 256;            // 196
    int NBK_H = (EP + 2047) / 2048;         // 416
    int NBK_M = (EP + 4095) / 4096;         // multisplit blocks (U=16)
    int NSETUP = 1 + NW2T + NA1 + NBK_H;

    float* f = (float*)d_ws;
    float* a_s1  = f;  f += (size_t)N * 8;
    float* a_d1  = f;  f += (size_t)N * 8;
    float* a_s2  = f;  f += N;
    float* a_d2  = f;  f += N;
    float4* w1t  = (float4*)f;  f += 480 * 4;
    float2* wa2t = (float2*)f;  f += 480 * 2;
    __half* h2buf = (__half*)f;
    __half* hp   = h2buf + (size_t)N * 480;
    __half* xh2h = hp;   hp += (size_t)N * 96;
    __half* w2t  = hp;   hp += 96 * 480;
    int2* ebuf   = (int2*)hp;
    int* ip      = (int*)(ebuf + EP);
    int* row_ptr = ip;  ip += N + 1;
    int* bcnt    = ip;  ip += MAXBUK;
    int* boff    = ip;  ip += MAXBUK + 1;
    int* bcursor = ip;  ip += MAXBUK;
    int* csr     = ip;  ip += EP;
    int* csrdst  = ip;  ip += EP;
    float* pbuf2 = (float*)ip;  ip += EP;

    size_t needed = (size_t)((char*)ip - (char*)d_ws);
    if (needed > ws_size) return;  // loud failure if scratch too small

    zero_bcnt<<<1, MAXBUK, 0, stream>>>(bcnt);
    setup_kernel<<<NSETUP, 256, 0, stream>>>(
        W1, as1, ad1, W2, as2, ad2, x, ei, E, N,
        w1t, wa2t, w2t, a_s1, a_d1, bcnt, NW2T, NA1);
    bucket_scan<<<1, 512, 0, stream>>>(bcnt, NBUK, boff, bcursor, row_ptr, N);
    multisplit<<<NBK_M, 256, 0, stream>>>(ei, E, N, bcursor, ebuf);
    csrfill2<<<NBUK, 256, 0, stream>>>(ebuf, boff, row_ptr, csr, csrdst, N);
    gat1_agg_h<<<(N + 3) / 4, 256, 0, stream>>>(
        row_ptr, csr, x, a_s1, a_d1, w1t, b1, wa2t, h2buf, a_s2, a_d2, N);
    p2_kernel<<<(EP + 1023) / 1024, 256, 0, stream>>>(
        csr, csrdst, a_s2, a_d2, pbuf2, EP);
    gemm2_mfma<<<(N + 63) / 64, 256, 0, stream>>>(h2buf, w2t, xh2h, N);
    gat2_fused<<<(N * 64 + 255) / 256, 256, 0, stream>>>(
        row_ptr, csr, pbuf2, xh2h, b2, out, N);
}